// Round 1
// baseline (723.335 us; speedup 1.0000x reference)
//
#include <hip/hip_runtime.h>
#include <math.h>

#define NPTS 1024
#define HEIGHT_B 32
#define WIDTH_B 32
#define WIN 7
#define CAND 224   // WIN*WIDTH_B
#define KEFF 64
#define BATCH 2
#define NEGV -1e30f

// ---------------------------------------------------------------- sq norms
__global__ __launch_bounds__(256) void ksq(const float* __restrict__ x, int bs, int Cin,
                                           float* __restrict__ sq) {
    int n = blockIdx.x * 256 + threadIdx.x;
    int b = blockIdx.y;
    const float* xb = x + (size_t)b * bs;
    float s = 0.f;
    for (int c = 0; c < Cin; ++c) { float v = xb[(size_t)c * NPTS + n]; s += v * v; }
    sq[b * NPTS + n] = s;
}

// ---------------------------------------------------------------- A = W1@x, Bv = (W2-W1)@x
__global__ __launch_bounds__(256) void kab(const float* __restrict__ x, int bs,
                                           const float* __restrict__ W, int Cin, int Co,
                                           float* __restrict__ A, float* __restrict__ Bv) {
    int n = blockIdx.x * 256 + threadIdx.x;
    int o = blockIdx.y;
    int b = blockIdx.z;
    const float* xb = x + (size_t)b * bs;
    const float* wr = W + (size_t)o * 2 * Cin;
    float a = 0.f, bb = 0.f;
    for (int c = 0; c < Cin; ++c) {
        float v = xb[(size_t)c * NPTS + n];
        a  = fmaf(wr[c], v, a);
        bb = fmaf(wr[Cin + c], v, bb);
    }
    size_t off = ((size_t)(b * Co + o)) * NPTS + n;
    A[off] = a;
    Bv[off] = bb - a;
}

// ---------------------------------------------------------------- banded gram partials
// grid: (nchunk, HEIGHT_B, BATCH); each chunk covers 64 channels (two 32-ch stages)
__global__ __launch_bounds__(256) void kdist(const float* __restrict__ x, int bs, int Cin,
                                             float* __restrict__ Dp) {
    __shared__ float Xc[32][CAND];   // 28672 B
    int chunk = blockIdx.x, i = blockIdx.y, b = blockIdx.z;
    int t = threadIdx.x;
    const float* xb = x + (size_t)b * bs;
    int q  = t >> 3;   // 0..31 query within block
    int wg = t & 7;    // w = wg*28 + j, j in [0,28)
    float acc[28];
#pragma unroll
    for (int j = 0; j < 28; ++j) acc[j] = 0.f;

    for (int sub = 0; sub < 2; ++sub) {
        int c0 = chunk * 64 + sub * 32;
        if (c0 >= Cin) break;   // uniform across block
        for (int e = t; e < 32 * CAND; e += 256) {
            int cc = e / CAND;
            int w  = e - cc * CAND;
            int wb = i - 3 + (w >> 5);
            wb = wb < 0 ? 0 : (wb > 31 ? 31 : wb);
            Xc[cc][w] = xb[(size_t)(c0 + cc) * NPTS + wb * 32 + (w & 31)];
        }
        __syncthreads();
        for (int cc = 0; cc < 32; ++cc) {
            float qv = Xc[cc][96 + q];   // query col is always window block j=3 (never clipped)
            const float4* row = (const float4*)&Xc[cc][wg * 28];
#pragma unroll
            for (int j4 = 0; j4 < 7; ++j4) {
                float4 v = row[j4];
                acc[j4 * 4 + 0] = fmaf(qv, v.x, acc[j4 * 4 + 0]);
                acc[j4 * 4 + 1] = fmaf(qv, v.y, acc[j4 * 4 + 1]);
                acc[j4 * 4 + 2] = fmaf(qv, v.z, acc[j4 * 4 + 2]);
                acc[j4 * 4 + 3] = fmaf(qv, v.w, acc[j4 * 4 + 3]);
            }
        }
        __syncthreads();
    }
    int n = i * 32 + q;
    size_t base = (((size_t)chunk * BATCH + b) * NPTS + n) * CAND + wg * 28;
    float4* outp = (float4*)&Dp[base];
#pragma unroll
    for (int j4 = 0; j4 < 7; ++j4)
        outp[j4] = make_float4(acc[j4 * 4], acc[j4 * 4 + 1], acc[j4 * 4 + 2], acc[j4 * 4 + 3]);
}

// ---------------------------------------------------------------- top-64 rank selection
// grid: (NPTS/4, BATCH); one wave per point
__global__ __launch_bounds__(256) void kselect(const float* __restrict__ Dp, int nchunk,
                                               const float* __restrict__ sq,
                                               int* __restrict__ idxo) {
    __shared__ float Dsh[4][CAND];
    int t = threadIdx.x;
    int wv = t >> 6, l = t & 63;
    int b = blockIdx.y;
    int n = blockIdx.x * 4 + wv;
    int i = n >> 5;
    float sqn = sq[b * NPTS + n];
    float v[4];
    int wid[4];
#pragma unroll
    for (int j = 0; j < 4; ++j) {
        int w = l + 64 * j;
        wid[j] = w;
        if (w < CAND) {
            size_t off = ((size_t)b * NPTS + n) * CAND + w;
            float s = 0.f;
            for (int ch = 0; ch < nchunk; ++ch)
                s += Dp[off + (size_t)ch * (BATCH * NPTS * CAND)];
            int wb = i - 3 + (w >> 5);
            bool valid = (wb >= 0) && (wb < 32);
            int wbc = wb < 0 ? 0 : (wb > 31 ? 31 : wb);
            float d = 2.f * s - sqn - sq[b * NPTS + wbc * 32 + (w & 31)];
            v[j] = valid ? d : NEGV;
            Dsh[wv][w] = v[j];
        } else {
            v[j] = NEGV;
        }
    }
    __syncthreads();
    int cnt[4] = {0, 0, 0, 0};
    const float4* row = (const float4*)Dsh[wv];
    for (int w4 = 0; w4 < CAND / 4; ++w4) {
        float4 dv = row[w4];
        int wp = w4 * 4;
#pragma unroll
        for (int j = 0; j < 4; ++j) {
            cnt[j] += (dv.x > v[j]) || (dv.x == v[j] && (wp + 0) < wid[j]);
            cnt[j] += (dv.y > v[j]) || (dv.y == v[j] && (wp + 1) < wid[j]);
            cnt[j] += (dv.z > v[j]) || (dv.z == v[j] && (wp + 2) < wid[j]);
            cnt[j] += (dv.w > v[j]) || (dv.w == v[j] && (wp + 3) < wid[j]);
        }
    }
#pragma unroll
    for (int j = 0; j < 4; ++j)
        if (wid[j] < CAND && cnt[j] < KEFF)
            idxo[((size_t)b * NPTS + n) * KEFF + cnt[j]] = (i - 3) * 32 + wid[j];
}

// ---------------------------------------------------------------- gather + max / S1 / S2 + stats partials
// grid: (Co, BATCH)
__global__ __launch_bounds__(256) void kagg(const float* __restrict__ A, const float* __restrict__ Bv,
                                            const int* __restrict__ idx, int Co,
                                            float* __restrict__ maxY, float* __restrict__ part) {
    __shared__ float Ash[NPTS];
    __shared__ float red[256];
    int o = blockIdx.x, b = blockIdx.y, t = threadIdx.x;
    size_t rowoff = ((size_t)(b * Co + o)) * NPTS;
    for (int r = 0; r < 4; ++r) Ash[r * 256 + t] = A[rowoff + r * 256 + t];
    __syncthreads();
    float sum = 0.f, sumsq = 0.f;
    for (int r = 0; r < 4; ++r) {
        int n = r * 256 + t;
        const int4* ip = (const int4*)&idx[((size_t)b * NPTS + n) * KEFF];
        float s1 = 0.f, s2 = 0.f, mx = -3.4e38f;
#pragma unroll
        for (int kk = 0; kk < KEFF / 4; ++kk) {
            int4 v4 = ip[kk];
            float a0 = Ash[v4.x], a1 = Ash[v4.y], a2 = Ash[v4.z], a3 = Ash[v4.w];
            s1 += a0 + a1 + a2 + a3;
            s2 += a0 * a0 + a1 * a1 + a2 * a2 + a3 * a3;
            mx = fmaxf(mx, fmaxf(fmaxf(a0, a1), fmaxf(a2, a3)));
        }
        float bv = Bv[rowoff + n];
        maxY[rowoff + n] = mx + bv;
        sum   += s1 + 64.f * bv;
        sumsq += s2 + 2.f * bv * s1 + 64.f * bv * bv;
    }
    red[t] = sum; __syncthreads();
    for (int s = 128; s > 0; s >>= 1) { if (t < s) red[t] += red[t + s]; __syncthreads(); }
    if (t == 0) part[((size_t)(b * Co + o)) * 2 + 0] = red[0];
    __syncthreads();
    red[t] = sumsq; __syncthreads();
    for (int s = 128; s > 0; s >>= 1) { if (t < s) red[t] += red[t + s]; __syncthreads(); }
    if (t == 0) part[((size_t)(b * Co + o)) * 2 + 1] = red[0];
}

// ---------------------------------------------------------------- BN affine + leaky, write into xcon slot
// grid: (Co, BATCH)
__global__ __launch_bounds__(256) void kfin(const float* __restrict__ maxY, const float* __restrict__ part,
                                            const float* __restrict__ g, const float* __restrict__ beta,
                                            int Co, float* __restrict__ xcon, int chOut) {
    int o = blockIdx.x, b = blockIdx.y, t = threadIdx.x;
    float s  = part[(size_t)o * 2 + 0] + part[((size_t)Co + o) * 2 + 0];
    float s2 = part[(size_t)o * 2 + 1] + part[((size_t)Co + o) * 2 + 1];
    const float invc = 1.f / (BATCH * NPTS * KEFF);
    float mu = s * invc;
    float var = s2 * invc - mu * mu;
    float rsig = rsqrtf(var + 1e-5f);
    float scale = g[o] * rsig;
    float shift = beta[o] - mu * scale;
    size_t inoff  = ((size_t)(b * Co + o)) * NPTS;
    size_t outoff = ((size_t)b * 384 + chOut + o) * NPTS;
    for (int r = 0; r < 4; ++r) {
        int n = r * 256 + t;
        float y = maxY[inoff + n] * scale + shift;
        xcon[outoff + n] = y >= 0.f ? y : 0.2f * y;
    }
}

// ---------------------------------------------------------------- final GEMM: out = w_last @ xcon
// grid: (NPTS/256, 384/16, BATCH)
__global__ __launch_bounds__(256) void kfinal(const float* __restrict__ xcon,
                                              const float* __restrict__ wl,
                                              float* __restrict__ out) {
    __shared__ float Xs[32][256];
    int t = threadIdx.x;
    int n0 = blockIdx.x * 256;
    int o0 = blockIdx.y * 16;
    int b = blockIdx.z;
    const float* xb = xcon + (size_t)b * 384 * NPTS + n0;
    float acc[16];
#pragma unroll
    for (int j = 0; j < 16; ++j) acc[j] = 0.f;
    for (int c0 = 0; c0 < 384; c0 += 32) {
        __syncthreads();
        for (int cc = 0; cc < 32; ++cc) Xs[cc][t] = xb[(size_t)(c0 + cc) * NPTS + t];
        __syncthreads();
        for (int cc = 0; cc < 32; ++cc) {
            float xv = Xs[cc][t];
#pragma unroll
            for (int j = 0; j < 16; ++j)
                acc[j] = fmaf(wl[(size_t)(o0 + j) * 384 + c0 + cc], xv, acc[j]);
        }
    }
#pragma unroll
    for (int j = 0; j < 16; ++j)
        out[((size_t)b * 384 + o0 + j) * NPTS + n0 + t] = acc[j];
}

extern "C" void kernel_launch(void* const* d_in, const int* in_sizes, int n_in,
                              void* d_out, int out_size, void* d_ws, size_t ws_size,
                              hipStream_t stream) {
    const float* x  = (const float*)d_in[0];
    const float* w[4]  = {(const float*)d_in[1], (const float*)d_in[4], (const float*)d_in[7], (const float*)d_in[10]};
    const float* g[4]  = {(const float*)d_in[2], (const float*)d_in[5], (const float*)d_in[8], (const float*)d_in[11]};
    const float* be[4] = {(const float*)d_in[3], (const float*)d_in[6], (const float*)d_in[9], (const float*)d_in[12]};
    const float* wl = (const float*)d_in[13];

    float* ws   = (float*)d_ws;
    float* xcon = ws;                       // 2*384*1024      = 786432
    float* A    = xcon + 786432;            // 2*128*1024      = 262144
    float* Bv   = A + 262144;               // 262144
    float* sq   = Bv + 262144;              // 2*1024          = 2048
    float* Dp   = sq + 2048;                // 4*2*1024*224    = 1835008
    float* maxY = Dp + 1835008;             // 262144
    float* part = maxY + 262144;            // 2*128*2         = 512 (pad to 1024)
    int*   idx  = (int*)(part + 1024);      // 2*1024*64       = 131072
    // total ~14.2 MB

    struct Cfg { const float* xin; int bs; int Cin; int Co; int chOut; };
    Cfg L[4] = {
        { x,                 256 * 1024, 256, 128, 0   },
        { xcon,              384 * 1024, 128, 128, 128 },
        { xcon + 128 * 1024, 384 * 1024, 128, 64,  256 },
        { xcon + 256 * 1024, 384 * 1024, 64,  64,  320 },
    };

    for (int l = 0; l < 4; ++l) {
        int Cin = L[l].Cin, Co = L[l].Co;
        int nch = (Cin + 63) / 64;
        ksq    <<<dim3(4, BATCH),          256, 0, stream>>>(L[l].xin, L[l].bs, Cin, sq);
        kab    <<<dim3(4, Co, BATCH),      256, 0, stream>>>(L[l].xin, L[l].bs, w[l], Cin, Co, A, Bv);
        kdist  <<<dim3(nch, HEIGHT_B, BATCH), 256, 0, stream>>>(L[l].xin, L[l].bs, Cin, Dp);
        kselect<<<dim3(NPTS / 4, BATCH),   256, 0, stream>>>(Dp, nch, sq, idx);
        kagg   <<<dim3(Co, BATCH),         256, 0, stream>>>(A, Bv, idx, Co, maxY, part);
        kfin   <<<dim3(Co, BATCH),         256, 0, stream>>>(maxY, part, g[l], be[l], Co, xcon, L[l].chOut);
    }
    kfinal<<<dim3(NPTS / 256, 384 / 16, BATCH), 256, 0, stream>>>(xcon, wl, (float*)d_out);
}

// Round 2
// 583.369 us; speedup vs baseline: 1.2399x; 1.2399x over previous
//
#include <hip/hip_runtime.h>
#include <math.h>

#define NPTS 1024
#define HEIGHT_B 32
#define WIDTH_B 32
#define WIN 7
#define CAND 224   // WIN*WIDTH_B
#define KEFF 64
#define BATCH 2
#define NEGV -1e30f

// ---------------------------------------------------------------- A = W1@x, Bv = (W2-W1)@x, sq(o==0)
__global__ __launch_bounds__(256) void kab(const float* __restrict__ x, int bs,
                                           const float* __restrict__ W, int Cin, int Co,
                                           float* __restrict__ A, float* __restrict__ Bv,
                                           float* __restrict__ sq) {
    int n = blockIdx.x * 256 + threadIdx.x;
    int o = blockIdx.y;
    int b = blockIdx.z;
    const float* xb = x + (size_t)b * bs;
    const float* wr = W + (size_t)o * 2 * Cin;
    float a = 0.f, bb = 0.f, s = 0.f;
    if (o == 0) {
        for (int c = 0; c < Cin; ++c) {
            float v = xb[(size_t)c * NPTS + n];
            a  = fmaf(wr[c], v, a);
            bb = fmaf(wr[Cin + c], v, bb);
            s  = fmaf(v, v, s);
        }
        sq[b * NPTS + n] = s;
    } else {
        for (int c = 0; c < Cin; ++c) {
            float v = xb[(size_t)c * NPTS + n];
            a  = fmaf(wr[c], v, a);
            bb = fmaf(wr[Cin + c], v, bb);
        }
    }
    size_t off = ((size_t)(b * Co + o)) * NPTS + n;
    A[off] = a;
    Bv[off] = bb - a;
}

// ---------------------------------------------------------------- banded gram partials
// grid: (nchunk, HEIGHT_B, BATCH); each chunk covers 64 channels (two 32-ch stages)
__global__ __launch_bounds__(256) void kdist(const float* __restrict__ x, int bs, int Cin,
                                             float* __restrict__ Dp) {
    __shared__ float Xc[32][CAND];   // 28672 B
    int chunk = blockIdx.x, i = blockIdx.y, b = blockIdx.z;
    int t = threadIdx.x;
    const float* xb = x + (size_t)b * bs;
    int q  = t >> 3;   // 0..31 query within block
    int wg = t & 7;    // w = wg*28 + j, j in [0,28)
    float acc[28];
#pragma unroll
    for (int j = 0; j < 28; ++j) acc[j] = 0.f;

    for (int sub = 0; sub < 2; ++sub) {
        int c0 = chunk * 64 + sub * 32;
        if (c0 >= Cin) break;   // uniform across block
        for (int e = t; e < 32 * CAND; e += 256) {
            int cc = e / CAND;
            int w  = e - cc * CAND;
            int wb = i - 3 + (w >> 5);
            wb = wb < 0 ? 0 : (wb > 31 ? 31 : wb);
            Xc[cc][w] = xb[(size_t)(c0 + cc) * NPTS + wb * 32 + (w & 31)];
        }
        __syncthreads();
        for (int cc = 0; cc < 32; ++cc) {
            float qv = Xc[cc][96 + q];   // query col is always window block j=3 (never clipped)
            const float4* row = (const float4*)&Xc[cc][wg * 28];
#pragma unroll
            for (int j4 = 0; j4 < 7; ++j4) {
                float4 v = row[j4];
                acc[j4 * 4 + 0] = fmaf(qv, v.x, acc[j4 * 4 + 0]);
                acc[j4 * 4 + 1] = fmaf(qv, v.y, acc[j4 * 4 + 1]);
                acc[j4 * 4 + 2] = fmaf(qv, v.z, acc[j4 * 4 + 2]);
                acc[j4 * 4 + 3] = fmaf(qv, v.w, acc[j4 * 4 + 3]);
            }
        }
        __syncthreads();
    }
    int n = i * 32 + q;
    size_t base = (((size_t)chunk * BATCH + b) * NPTS + n) * CAND + wg * 28;
    float4* outp = (float4*)&Dp[base];
#pragma unroll
    for (int j4 = 0; j4 < 7; ++j4)
        outp[j4] = make_float4(acc[j4 * 4], acc[j4 * 4 + 1], acc[j4 * 4 + 2], acc[j4 * 4 + 3]);
}

// ---------------------------------------------------------------- top-64 rank selection
// grid: (NPTS/4, BATCH); one wave per point
__global__ __launch_bounds__(256) void kselect(const float* __restrict__ Dp, int nchunk,
                                               const float* __restrict__ sq,
                                               int* __restrict__ idxo) {
    __shared__ float Dsh[4][CAND];
    int t = threadIdx.x;
    int wv = t >> 6, l = t & 63;
    int b = blockIdx.y;
    int n = blockIdx.x * 4 + wv;
    int i = n >> 5;
    float sqn = sq[b * NPTS + n];
    float v[4];
    int wid[4];
#pragma unroll
    for (int j = 0; j < 4; ++j) {
        int w = l + 64 * j;
        wid[j] = w;
        if (w < CAND) {
            size_t off = ((size_t)b * NPTS + n) * CAND + w;
            float s = 0.f;
            for (int ch = 0; ch < nchunk; ++ch)
                s += Dp[off + (size_t)ch * (BATCH * NPTS * CAND)];
            int wb = i - 3 + (w >> 5);
            bool valid = (wb >= 0) && (wb < 32);
            int wbc = wb < 0 ? 0 : (wb > 31 ? 31 : wb);
            float d = 2.f * s - sqn - sq[b * NPTS + wbc * 32 + (w & 31)];
            v[j] = valid ? d : NEGV;
            Dsh[wv][w] = v[j];
        } else {
            v[j] = NEGV;
        }
    }
    __syncthreads();
    int cnt[4] = {0, 0, 0, 0};
    const float4* row = (const float4*)Dsh[wv];
    for (int w4 = 0; w4 < CAND / 4; ++w4) {
        float4 dv = row[w4];
        int wp = w4 * 4;
#pragma unroll
        for (int j = 0; j < 4; ++j) {
            cnt[j] += (dv.x > v[j]) || (dv.x == v[j] && (wp + 0) < wid[j]);
            cnt[j] += (dv.y > v[j]) || (dv.y == v[j] && (wp + 1) < wid[j]);
            cnt[j] += (dv.z > v[j]) || (dv.z == v[j] && (wp + 2) < wid[j]);
            cnt[j] += (dv.w > v[j]) || (dv.w == v[j] && (wp + 3) < wid[j]);
        }
    }
#pragma unroll
    for (int j = 0; j < 4; ++j)
        if (wid[j] < CAND && cnt[j] < KEFF)
            idxo[((size_t)b * NPTS + n) * KEFF + cnt[j]] = (i - 3) * 32 + wid[j];
}

// ---------------------------------------------------------------- gather + max / S1 / S2 + stats partials
// grid: (Co, BATCH)
__global__ __launch_bounds__(256) void kagg(const float* __restrict__ A, const float* __restrict__ Bv,
                                            const int* __restrict__ idx, int Co,
                                            float* __restrict__ maxY, float* __restrict__ part) {
    __shared__ float Ash[NPTS];
    __shared__ float red[256];
    int o = blockIdx.x, b = blockIdx.y, t = threadIdx.x;
    size_t rowoff = ((size_t)(b * Co + o)) * NPTS;
    for (int r = 0; r < 4; ++r) Ash[r * 256 + t] = A[rowoff + r * 256 + t];
    __syncthreads();
    float sum = 0.f, sumsq = 0.f;
    for (int r = 0; r < 4; ++r) {
        int n = r * 256 + t;
        const int4* ip = (const int4*)&idx[((size_t)b * NPTS + n) * KEFF];
        float s1 = 0.f, s2 = 0.f, mx = -3.4e38f;
#pragma unroll
        for (int kk = 0; kk < KEFF / 4; ++kk) {
            int4 v4 = ip[kk];
            float a0 = Ash[v4.x], a1 = Ash[v4.y], a2 = Ash[v4.z], a3 = Ash[v4.w];
            s1 += a0 + a1 + a2 + a3;
            s2 += a0 * a0 + a1 * a1 + a2 * a2 + a3 * a3;
            mx = fmaxf(mx, fmaxf(fmaxf(a0, a1), fmaxf(a2, a3)));
        }
        float bv = Bv[rowoff + n];
        maxY[rowoff + n] = mx + bv;
        sum   += s1 + 64.f * bv;
        sumsq += s2 + 2.f * bv * s1 + 64.f * bv * bv;
    }
    red[t] = sum; __syncthreads();
    for (int s = 128; s > 0; s >>= 1) { if (t < s) red[t] += red[t + s]; __syncthreads(); }
    if (t == 0) part[((size_t)(b * Co + o)) * 2 + 0] = red[0];
    __syncthreads();
    red[t] = sumsq; __syncthreads();
    for (int s = 128; s > 0; s >>= 1) { if (t < s) red[t] += red[t + s]; __syncthreads(); }
    if (t == 0) part[((size_t)(b * Co + o)) * 2 + 1] = red[0];
}

// ---------------------------------------------------------------- BN affine + leaky, write into xcon slot
// grid: (Co, BATCH)
__global__ __launch_bounds__(256) void kfin(const float* __restrict__ maxY, const float* __restrict__ part,
                                            const float* __restrict__ g, const float* __restrict__ beta,
                                            int Co, float* __restrict__ xcon, int chOut) {
    int o = blockIdx.x, b = blockIdx.y, t = threadIdx.x;
    float s  = part[(size_t)o * 2 + 0] + part[((size_t)Co + o) * 2 + 0];
    float s2 = part[(size_t)o * 2 + 1] + part[((size_t)Co + o) * 2 + 1];
    const float invc = 1.f / (BATCH * NPTS * KEFF);
    float mu = s * invc;
    float var = s2 * invc - mu * mu;
    float rsig = rsqrtf(var + 1e-5f);
    float scale = g[o] * rsig;
    float shift = beta[o] - mu * scale;
    size_t inoff  = ((size_t)(b * Co + o)) * NPTS;
    size_t outoff = ((size_t)b * 384 + chOut + o) * NPTS;
    for (int r = 0; r < 4; ++r) {
        int n = r * 256 + t;
        float y = maxY[inoff + n] * scale + shift;
        xcon[outoff + n] = y >= 0.f ? y : 0.2f * y;
    }
}

// ---------------------------------------------------------------- final GEMM: out = w_last @ xcon
// grid: (NPTS/256, 384/16, BATCH)
__global__ __launch_bounds__(256) void kfinal(const float* __restrict__ xcon,
                                              const float* __restrict__ wl,
                                              float* __restrict__ out) {
    __shared__ float Xs[32][256];
    int t = threadIdx.x;
    int n0 = blockIdx.x * 256;
    int o0 = blockIdx.y * 16;
    int b = blockIdx.z;
    const float* xb = xcon + (size_t)b * 384 * NPTS + n0;
    float acc[16];
#pragma unroll
    for (int j = 0; j < 16; ++j) acc[j] = 0.f;
    for (int c0 = 0; c0 < 384; c0 += 32) {
        __syncthreads();
        for (int cc = 0; cc < 32; ++cc) Xs[cc][t] = xb[(size_t)(c0 + cc) * NPTS + t];
        __syncthreads();
        for (int cc = 0; cc < 32; ++cc) {
            float xv = Xs[cc][t];
#pragma unroll
            for (int j = 0; j < 16; ++j)
                acc[j] = fmaf(wl[(size_t)(o0 + j) * 384 + c0 + cc], xv, acc[j]);
        }
    }
#pragma unroll
    for (int j = 0; j < 16; ++j)
        out[((size_t)b * 384 + o0 + j) * NPTS + n0 + t] = acc[j];
}

extern "C" void kernel_launch(void* const* d_in, const int* in_sizes, int n_in,
                              void* d_out, int out_size, void* d_ws, size_t ws_size,
                              hipStream_t stream) {
    const float* x  = (const float*)d_in[0];
    const float* w[4]  = {(const float*)d_in[1], (const float*)d_in[4], (const float*)d_in[7], (const float*)d_in[10]};
    const float* g[4]  = {(const float*)d_in[2], (const float*)d_in[5], (const float*)d_in[8], (const float*)d_in[11]};
    const float* be[4] = {(const float*)d_in[3], (const float*)d_in[6], (const float*)d_in[9], (const float*)d_in[12]};
    const float* wl = (const float*)d_in[13];

    float* ws   = (float*)d_ws;
    float* xcon = ws;                       // 2*384*1024      = 786432
    float* A    = xcon + 786432;            // 2*128*1024      = 262144
    float* Bv   = A + 262144;               // 262144
    float* sq   = Bv + 262144;              // 2*1024          = 2048
    float* Dp   = sq + 2048;                // 4*2*1024*224    = 1835008
    float* maxY = Dp + 1835008;             // 262144
    float* part = maxY + 262144;            // 2*128*2         = 512 (pad to 1024)
    int*   idx  = (int*)(part + 1024);      // 2*1024*64       = 131072
    // total ~14.2 MB

    struct Cfg { const float* xin; int bs; int Cin; int Co; int chOut; };
    Cfg L[4] = {
        { x,                 256 * 1024, 256, 128, 0   },
        { xcon,              384 * 1024, 128, 128, 128 },
        { xcon + 128 * 1024, 384 * 1024, 128, 64,  256 },
        { xcon + 256 * 1024, 384 * 1024, 64,  64,  320 },
    };

    for (int l = 0; l < 4; ++l) {
        int Cin = L[l].Cin, Co = L[l].Co;
        int nch = (Cin + 63) / 64;
        kab    <<<dim3(4, Co, BATCH),      256, 0, stream>>>(L[l].xin, L[l].bs, w[l], Cin, Co, A, Bv, sq);
        kdist  <<<dim3(nch, HEIGHT_B, BATCH), 256, 0, stream>>>(L[l].xin, L[l].bs, Cin, Dp);
        kselect<<<dim3(NPTS / 4, BATCH),   256, 0, stream>>>(Dp, nch, sq, idx);
        kagg   <<<dim3(Co, BATCH),         256, 0, stream>>>(A, Bv, idx, Co, maxY, part);
        kfin   <<<dim3(Co, BATCH),         256, 0, stream>>>(maxY, part, g[l], be[l], Co, xcon, L[l].chOut);
    }
    kfinal<<<dim3(NPTS / 256, 384 / 16, BATCH), 256, 0, stream>>>(xcon, wl, (float*)d_out);
}

// Round 3
// 567.144 us; speedup vs baseline: 1.2754x; 1.0286x over previous
//
#include <hip/hip_runtime.h>
#include <math.h>

#define NPTS 1024
#define HEIGHT_B 32
#define WIDTH_B 32
#define WIN 7
#define CAND 224   // WIN*WIDTH_B
#define KEFF 64
#define BATCH 2
#define NEGV -1e30f

// ---------------------------------------------------------------- A = W1@x, Bv = (W2-W1)@x, sq
// Tiled GEMM: block = 64 n-points x 64 o-channels; thread = 4o x 4n register tile.
// grid: (NPTS/64, (Co+63)/64, BATCH), block 256
__global__ __launch_bounds__(256) void kab(const float* __restrict__ x, int bs,
                                           const float* __restrict__ W, int Cin, int Co,
                                           float* __restrict__ A, float* __restrict__ Bv,
                                           float* __restrict__ sq) {
    __shared__ float Xs[32][64];       // [c][n]  8 KB
    __shared__ float Wta[32][68];      // [c][o] transposed, pad 68 (272B rows, 16B aligned)
    __shared__ float Wtb[32][68];
    int t = threadIdx.x;
    int tn4 = (t & 15) * 4;            // n offset within tile
    int to4 = (t >> 4) * 4;            // o offset within tile
    int n0 = blockIdx.x * 64;
    int o0 = blockIdx.y * 64;
    int b  = blockIdx.z;
    const float* xb = x + (size_t)b * bs + n0;

    float4 a[4], bb[4], s4;
#pragma unroll
    for (int i = 0; i < 4; ++i) { a[i] = make_float4(0.f,0.f,0.f,0.f); bb[i] = make_float4(0.f,0.f,0.f,0.f); }
    s4 = make_float4(0.f,0.f,0.f,0.f);

    for (int c0 = 0; c0 < Cin; c0 += 32) {
        for (int e = t; e < 32 * 64; e += 256) {
            int cc = e >> 6, nn = e & 63;
            Xs[cc][nn] = xb[(size_t)(c0 + cc) * NPTS + nn];
        }
        for (int e = t; e < 32 * 64; e += 256) {
            int cc = e >> 6, oo = e & 63;
            const float* wp = W + (size_t)(o0 + oo) * 2 * Cin + c0 + cc;
            Wta[cc][oo] = wp[0];
            Wtb[cc][oo] = wp[Cin];
        }
        __syncthreads();
#pragma unroll 4
        for (int cc = 0; cc < 32; ++cc) {
            float4 xv = *(const float4*)&Xs[cc][tn4];
            float4 wa = *(const float4*)&Wta[cc][to4];
            float4 wb = *(const float4*)&Wtb[cc][to4];
            s4.x = fmaf(xv.x, xv.x, s4.x);
            s4.y = fmaf(xv.y, xv.y, s4.y);
            s4.z = fmaf(xv.z, xv.z, s4.z);
            s4.w = fmaf(xv.w, xv.w, s4.w);
            float wav[4] = {wa.x, wa.y, wa.z, wa.w};
            float wbv[4] = {wb.x, wb.y, wb.z, wb.w};
#pragma unroll
            for (int i = 0; i < 4; ++i) {
                a[i].x  = fmaf(wav[i], xv.x, a[i].x);
                a[i].y  = fmaf(wav[i], xv.y, a[i].y);
                a[i].z  = fmaf(wav[i], xv.z, a[i].z);
                a[i].w  = fmaf(wav[i], xv.w, a[i].w);
                bb[i].x = fmaf(wbv[i], xv.x, bb[i].x);
                bb[i].y = fmaf(wbv[i], xv.y, bb[i].y);
                bb[i].z = fmaf(wbv[i], xv.z, bb[i].z);
                bb[i].w = fmaf(wbv[i], xv.w, bb[i].w);
            }
        }
        __syncthreads();
    }

    int n = n0 + tn4;
    if (to4 == 0 && blockIdx.y == 0)
        *(float4*)&sq[b * NPTS + n] = s4;
#pragma unroll
    for (int i = 0; i < 4; ++i) {
        int o = o0 + to4 + i;
        size_t off = ((size_t)(b * Co + o)) * NPTS + n;
        *(float4*)&A[off] = a[i];
        *(float4*)&Bv[off] = make_float4(bb[i].x - a[i].x, bb[i].y - a[i].y,
                                         bb[i].z - a[i].z, bb[i].w - a[i].w);
    }
}

// ---------------------------------------------------------------- banded gram partials
// grid: (nchunk, HEIGHT_B, BATCH); each chunk covers 64 channels (two 32-ch stages)
__global__ __launch_bounds__(256) void kdist(const float* __restrict__ x, int bs, int Cin,
                                             float* __restrict__ Dp) {
    __shared__ float Xc[32][CAND];   // 28672 B
    int chunk = blockIdx.x, i = blockIdx.y, b = blockIdx.z;
    int t = threadIdx.x;
    const float* xb = x + (size_t)b * bs;
    int q  = t >> 3;   // 0..31 query within block
    int wg = t & 7;    // w = wg*28 + j, j in [0,28)
    float acc[28];
#pragma unroll
    for (int j = 0; j < 28; ++j) acc[j] = 0.f;

    for (int sub = 0; sub < 2; ++sub) {
        int c0 = chunk * 64 + sub * 32;
        if (c0 >= Cin) break;   // uniform across block
        for (int e = t; e < 32 * CAND; e += 256) {
            int cc = e / CAND;
            int w  = e - cc * CAND;
            int wb = i - 3 + (w >> 5);
            wb = wb < 0 ? 0 : (wb > 31 ? 31 : wb);
            Xc[cc][w] = xb[(size_t)(c0 + cc) * NPTS + wb * 32 + (w & 31)];
        }
        __syncthreads();
        for (int cc = 0; cc < 32; ++cc) {
            float qv = Xc[cc][96 + q];   // query col is always window block j=3 (never clipped)
            const float4* row = (const float4*)&Xc[cc][wg * 28];
#pragma unroll
            for (int j4 = 0; j4 < 7; ++j4) {
                float4 v = row[j4];
                acc[j4 * 4 + 0] = fmaf(qv, v.x, acc[j4 * 4 + 0]);
                acc[j4 * 4 + 1] = fmaf(qv, v.y, acc[j4 * 4 + 1]);
                acc[j4 * 4 + 2] = fmaf(qv, v.z, acc[j4 * 4 + 2]);
                acc[j4 * 4 + 3] = fmaf(qv, v.w, acc[j4 * 4 + 3]);
            }
        }
        __syncthreads();
    }
    int n = i * 32 + q;
    size_t base = (((size_t)chunk * BATCH + b) * NPTS + n) * CAND + wg * 28;
    float4* outp = (float4*)&Dp[base];
#pragma unroll
    for (int j4 = 0; j4 < 7; ++j4)
        outp[j4] = make_float4(acc[j4 * 4], acc[j4 * 4 + 1], acc[j4 * 4 + 2], acc[j4 * 4 + 3]);
}

// ---------------------------------------------------------------- top-64 rank selection
// grid: (NPTS/4, BATCH); one wave per point
__global__ __launch_bounds__(256) void kselect(const float* __restrict__ Dp, int nchunk,
                                               const float* __restrict__ sq,
                                               int* __restrict__ idxo) {
    __shared__ float Dsh[4][CAND];
    int t = threadIdx.x;
    int wv = t >> 6, l = t & 63;
    int b = blockIdx.y;
    int n = blockIdx.x * 4 + wv;
    int i = n >> 5;
    float sqn = sq[b * NPTS + n];
    float v[4];
    int wid[4];
#pragma unroll
    for (int j = 0; j < 4; ++j) {
        int w = l + 64 * j;
        wid[j] = w;
        if (w < CAND) {
            size_t off = ((size_t)b * NPTS + n) * CAND + w;
            float s = 0.f;
            for (int ch = 0; ch < nchunk; ++ch)
                s += Dp[off + (size_t)ch * (BATCH * NPTS * CAND)];
            int wb = i - 3 + (w >> 5);
            bool valid = (wb >= 0) && (wb < 32);
            int wbc = wb < 0 ? 0 : (wb > 31 ? 31 : wb);
            float d = 2.f * s - sqn - sq[b * NPTS + wbc * 32 + (w & 31)];
            v[j] = valid ? d : NEGV;
            Dsh[wv][w] = v[j];
        } else {
            v[j] = NEGV;
        }
    }
    __syncthreads();
    int cnt[4] = {0, 0, 0, 0};
    const float4* row = (const float4*)Dsh[wv];
    for (int w4 = 0; w4 < CAND / 4; ++w4) {
        float4 dv = row[w4];
        int wp = w4 * 4;
#pragma unroll
        for (int j = 0; j < 4; ++j) {
            cnt[j] += (dv.x > v[j]) || (dv.x == v[j] && (wp + 0) < wid[j]);
            cnt[j] += (dv.y > v[j]) || (dv.y == v[j] && (wp + 1) < wid[j]);
            cnt[j] += (dv.z > v[j]) || (dv.z == v[j] && (wp + 2) < wid[j]);
            cnt[j] += (dv.w > v[j]) || (dv.w == v[j] && (wp + 3) < wid[j]);
        }
    }
#pragma unroll
    for (int j = 0; j < 4; ++j)
        if (wid[j] < CAND && cnt[j] < KEFF)
            idxo[((size_t)b * NPTS + n) * KEFF + cnt[j]] = (i - 3) * 32 + wid[j];
}

// ---------------------------------------------------------------- gather + max / S1 / S2 + stats partials
// grid: (Co, BATCH)
__global__ __launch_bounds__(256) void kagg(const float* __restrict__ A, const float* __restrict__ Bv,
                                            const int* __restrict__ idx, int Co,
                                            float* __restrict__ maxY, float* __restrict__ part) {
    __shared__ float Ash[NPTS];
    __shared__ float red[256];
    int o = blockIdx.x, b = blockIdx.y, t = threadIdx.x;
    size_t rowoff = ((size_t)(b * Co + o)) * NPTS;
    for (int r = 0; r < 4; ++r) Ash[r * 256 + t] = A[rowoff + r * 256 + t];
    __syncthreads();
    float sum = 0.f, sumsq = 0.f;
    for (int r = 0; r < 4; ++r) {
        int n = r * 256 + t;
        const int4* ip = (const int4*)&idx[((size_t)b * NPTS + n) * KEFF];
        float s1 = 0.f, s2 = 0.f, mx = -3.4e38f;
#pragma unroll
        for (int kk = 0; kk < KEFF / 4; ++kk) {
            int4 v4 = ip[kk];
            float a0 = Ash[v4.x], a1 = Ash[v4.y], a2 = Ash[v4.z], a3 = Ash[v4.w];
            s1 += a0 + a1 + a2 + a3;
            s2 += a0 * a0 + a1 * a1 + a2 * a2 + a3 * a3;
            mx = fmaxf(mx, fmaxf(fmaxf(a0, a1), fmaxf(a2, a3)));
        }
        float bv = Bv[rowoff + n];
        maxY[rowoff + n] = mx + bv;
        sum   += s1 + 64.f * bv;
        sumsq += s2 + 2.f * bv * s1 + 64.f * bv * bv;
    }
    red[t] = sum; __syncthreads();
    for (int s = 128; s > 0; s >>= 1) { if (t < s) red[t] += red[t + s]; __syncthreads(); }
    if (t == 0) part[((size_t)(b * Co + o)) * 2 + 0] = red[0];
    __syncthreads();
    red[t] = sumsq; __syncthreads();
    for (int s = 128; s > 0; s >>= 1) { if (t < s) red[t] += red[t + s]; __syncthreads(); }
    if (t == 0) part[((size_t)(b * Co + o)) * 2 + 1] = red[0];
}

// ---------------------------------------------------------------- BN affine + leaky, write into xcon slot
// grid: (Co, BATCH)
__global__ __launch_bounds__(256) void kfin(const float* __restrict__ maxY, const float* __restrict__ part,
                                            const float* __restrict__ g, const float* __restrict__ beta,
                                            int Co, float* __restrict__ xcon, int chOut) {
    int o = blockIdx.x, b = blockIdx.y, t = threadIdx.x;
    float s  = part[(size_t)o * 2 + 0] + part[((size_t)Co + o) * 2 + 0];
    float s2 = part[(size_t)o * 2 + 1] + part[((size_t)Co + o) * 2 + 1];
    const float invc = 1.f / (BATCH * NPTS * KEFF);
    float mu = s * invc;
    float var = s2 * invc - mu * mu;
    float rsig = rsqrtf(var + 1e-5f);
    float scale = g[o] * rsig;
    float shift = beta[o] - mu * scale;
    size_t inoff  = ((size_t)(b * Co + o)) * NPTS;
    size_t outoff = ((size_t)b * 384 + chOut + o) * NPTS;
    for (int r = 0; r < 4; ++r) {
        int n = r * 256 + t;
        float y = maxY[inoff + n] * scale + shift;
        xcon[outoff + n] = y >= 0.f ? y : 0.2f * y;
    }
}

// ---------------------------------------------------------------- final GEMM: out = w_last @ xcon
// grid: (NPTS/256, 384/16, BATCH)
__global__ __launch_bounds__(256) void kfinal(const float* __restrict__ xcon,
                                              const float* __restrict__ wl,
                                              float* __restrict__ out) {
    __shared__ float Xs[32][256];
    int t = threadIdx.x;
    int n0 = blockIdx.x * 256;
    int o0 = blockIdx.y * 16;
    int b = blockIdx.z;
    const float* xb = xcon + (size_t)b * 384 * NPTS + n0;
    float acc[16];
#pragma unroll
    for (int j = 0; j < 16; ++j) acc[j] = 0.f;
    for (int c0 = 0; c0 < 384; c0 += 32) {
        __syncthreads();
        for (int cc = 0; cc < 32; ++cc) Xs[cc][t] = xb[(size_t)(c0 + cc) * NPTS + t];
        __syncthreads();
        for (int cc = 0; cc < 32; ++cc) {
            float xv = Xs[cc][t];
#pragma unroll
            for (int j = 0; j < 16; ++j)
                acc[j] = fmaf(wl[(size_t)(o0 + j) * 384 + c0 + cc], xv, acc[j]);
        }
    }
#pragma unroll
    for (int j = 0; j < 16; ++j)
        out[((size_t)b * 384 + o0 + j) * NPTS + n0 + t] = acc[j];
}

extern "C" void kernel_launch(void* const* d_in, const int* in_sizes, int n_in,
                              void* d_out, int out_size, void* d_ws, size_t ws_size,
                              hipStream_t stream) {
    const float* x  = (const float*)d_in[0];
    const float* w[4]  = {(const float*)d_in[1], (const float*)d_in[4], (const float*)d_in[7], (const float*)d_in[10]};
    const float* g[4]  = {(const float*)d_in[2], (const float*)d_in[5], (const float*)d_in[8], (const float*)d_in[11]};
    const float* be[4] = {(const float*)d_in[3], (const float*)d_in[6], (const float*)d_in[9], (const float*)d_in[12]};
    const float* wl = (const float*)d_in[13];

    float* ws   = (float*)d_ws;
    float* xcon = ws;                       // 2*384*1024      = 786432
    float* A    = xcon + 786432;            // 2*128*1024      = 262144
    float* Bv   = A + 262144;               // 262144
    float* sq   = Bv + 262144;              // 2*1024          = 2048
    float* Dp   = sq + 2048;                // 4*2*1024*224    = 1835008
    float* maxY = Dp + 1835008;             // 262144
    float* part = maxY + 262144;            // 2*128*2         = 512 (pad to 1024)
    int*   idx  = (int*)(part + 1024);      // 2*1024*64       = 131072
    // total ~14.2 MB

    struct Cfg { const float* xin; int bs; int Cin; int Co; int chOut; };
    Cfg L[4] = {
        { x,                 256 * 1024, 256, 128, 0   },
        { xcon,              384 * 1024, 128, 128, 128 },
        { xcon + 128 * 1024, 384 * 1024, 128, 64,  256 },
        { xcon + 256 * 1024, 384 * 1024, 64,  64,  320 },
    };

    for (int l = 0; l < 4; ++l) {
        int Cin = L[l].Cin, Co = L[l].Co;
        int nch = (Cin + 63) / 64;
        kab    <<<dim3(NPTS / 64, (Co + 63) / 64, BATCH), 256, 0, stream>>>(L[l].xin, L[l].bs, w[l], Cin, Co, A, Bv, sq);
        kdist  <<<dim3(nch, HEIGHT_B, BATCH), 256, 0, stream>>>(L[l].xin, L[l].bs, Cin, Dp);
        kselect<<<dim3(NPTS / 4, BATCH),   256, 0, stream>>>(Dp, nch, sq, idx);
        kagg   <<<dim3(Co, BATCH),         256, 0, stream>>>(A, Bv, idx, Co, maxY, part);
        kfin   <<<dim3(Co, BATCH),         256, 0, stream>>>(maxY, part, g[l], be[l], Co, xcon, L[l].chOut);
    }
    kfinal<<<dim3(NPTS / 256, 384 / 16, BATCH), 256, 0, stream>>>(xcon, wl, (float*)d_out);
}

// Round 4
// 493.484 us; speedup vs baseline: 1.4658x; 1.1493x over previous
//
#include <hip/hip_runtime.h>
#include <math.h>

#define NPTS 1024
#define CAND 224   // 7*32
#define KEFF 64
#define BATCH 2
#define NEGV -1e30f

// ================================================================ weight prep
// Transpose weights to c-major once per call. 32x32 tiles via LDS.
// layout in wt (floats): wtA0@0(32768) wtB0@32768 wtA1@65536(16384) wtB1@81920
//   wtA2@98304(8192) wtB2@106496 wtA3@114688(4096) wtB3@118784 wlT@122880(147456)
__global__ __launch_bounds__(256) void kprep(const float* __restrict__ w0, const float* __restrict__ w1,
                                             const float* __restrict__ w2, const float* __restrict__ w3,
                                             const float* __restrict__ wl, float* __restrict__ wt) {
    __shared__ float tA[32][33];
    __shared__ float tB[32][33];
    int id = blockIdx.x;
    int t = threadIdx.x;
    int row = t >> 5, col = t & 31;
    const float* W = w0; int Cin = 256, Co = 128; float* WtA = wt; float* WtB = wt + 32768;
    int tc = 0, to = 0; bool isWL = false;
    if (id < 32)      { int r = id;      tc = r >> 2; to = r & 3; }
    else if (id < 48) { W = w1; Cin = 128; Co = 128; WtA = wt + 65536;  WtB = wt + 81920;  int r = id - 32; tc = r >> 2; to = r & 3; }
    else if (id < 56) { W = w2; Cin = 128; Co = 64;  WtA = wt + 98304;  WtB = wt + 106496; int r = id - 48; tc = r >> 1; to = r & 1; }
    else if (id < 60) { W = w3; Cin = 64;  Co = 64;  WtA = wt + 114688; WtB = wt + 118784; int r = id - 56; tc = r >> 1; to = r & 1; }
    else { isWL = true; int r = id - 60; tc = r / 12; to = r % 12; }
    if (!isWL) {
#pragma unroll
        for (int r = 0; r < 4; ++r) {
            int o = to * 32 + row + r * 8;
            int c = tc * 32 + col;
            float va = W[(size_t)o * 2 * Cin + c];
            tA[row + r * 8][col] = va;
            tB[row + r * 8][col] = W[(size_t)o * 2 * Cin + Cin + c] - va;
        }
        __syncthreads();
#pragma unroll
        for (int r = 0; r < 4; ++r) {
            int c = tc * 32 + row + r * 8;
            int o = to * 32 + col;
            WtA[(size_t)c * Co + o] = tA[col][row + r * 8];
            WtB[(size_t)c * Co + o] = tB[col][row + r * 8];
        }
    } else {
        float* wlT = wt + 122880;
#pragma unroll
        for (int r = 0; r < 4; ++r) {
            int o = to * 32 + row + r * 8;
            int c = tc * 32 + col;
            tA[row + r * 8][col] = wl[(size_t)o * 384 + c];
        }
        __syncthreads();
#pragma unroll
        for (int r = 0; r < 4; ++r) {
            int c = tc * 32 + row + r * 8;
            int o = to * 32 + col;
            wlT[(size_t)c * 384 + o] = tA[col][row + r * 8];
        }
    }
}

// ================================================================ fused GEMM (A/Bv/sq) + banded gram
struct GP {
    const float* xin; int bstride; int Cin; int Co; int nch; int applyBN;
    const float* WtA; const float* WtB;
    const float* partPrev; const float* gPrev; const float* bePrev;
    float* A; float* Bv; float* sq; float* Dp;
};

__global__ __launch_bounds__(256) void kgemm(GP p) {
    __shared__ float smem[7168];      // roleA: Xs[0..2047], Wta[2048..4223], Wtb[4224..6399]; roleB: Xc[32][224]
    __shared__ float shsc[128];
    __shared__ float shsh[128];
    int t = threadIdx.x;
    if (p.applyBN && t < p.Cin) {
        const float* pp = p.partPrev;
        float s  = pp[t * 2]     + pp[(p.Cin + t) * 2];
        float s2 = pp[t * 2 + 1] + pp[(p.Cin + t) * 2 + 1];
        const float invc = 1.f / 131072.f;
        float mu = s * invc;
        float var = s2 * invc - mu * mu;
        float rs = rsqrtf(var + 1e-5f);
        float sc = p.gPrev[t] * rs;
        shsc[t] = sc;
        shsh[t] = p.bePrev[t] - mu * sc;
    }
    __syncthreads();
    int nABx = 16 * (p.Co >> 6) * BATCH;
    if ((int)blockIdx.x < nABx) {
        // ---------------- role A: A = WtA^T x, Bv = WtB^T x, sq
        int id = blockIdx.x;
        int nt = id & 15; int rest = id >> 4;
        int nOT = p.Co >> 6;
        int ot = rest % nOT; int b = rest / nOT;
        int tn4 = (t & 15) * 4, to4 = (t >> 4) * 4;
        int n0 = nt * 64, o0 = ot * 64;
        const float* xb = p.xin + (size_t)b * p.bstride + n0;
        float* Xs = smem; float* Wta = smem + 2048; float* Wtb = smem + 4224;
        float4 a[4], bb[4], s4;
#pragma unroll
        for (int i = 0; i < 4; ++i) { a[i] = make_float4(0.f,0.f,0.f,0.f); bb[i] = make_float4(0.f,0.f,0.f,0.f); }
        s4 = make_float4(0.f,0.f,0.f,0.f);
        for (int c0 = 0; c0 < p.Cin; c0 += 32) {
            for (int e = t; e < 2048; e += 256) {
                int cc = e >> 6, nn = e & 63;
                float v = xb[(size_t)(c0 + cc) * NPTS + nn];
                if (p.applyBN) { float y = fmaf(v, shsc[c0 + cc], shsh[c0 + cc]); v = y >= 0.f ? y : 0.2f * y; }
                Xs[cc * 64 + nn] = v;
            }
            for (int e = t; e < 2048; e += 256) {
                int cc = e >> 6, oo = e & 63;
                Wta[cc * 68 + oo] = p.WtA[(size_t)(c0 + cc) * p.Co + o0 + oo];
                Wtb[cc * 68 + oo] = p.WtB[(size_t)(c0 + cc) * p.Co + o0 + oo];
            }
            __syncthreads();
#pragma unroll 4
            for (int cc = 0; cc < 32; ++cc) {
                float4 xv = *(const float4*)&Xs[cc * 64 + tn4];
                float4 wa = *(const float4*)&Wta[cc * 68 + to4];
                float4 wb = *(const float4*)&Wtb[cc * 68 + to4];
                s4.x = fmaf(xv.x, xv.x, s4.x);
                s4.y = fmaf(xv.y, xv.y, s4.y);
                s4.z = fmaf(xv.z, xv.z, s4.z);
                s4.w = fmaf(xv.w, xv.w, s4.w);
                float wav[4] = {wa.x, wa.y, wa.z, wa.w};
                float wbv[4] = {wb.x, wb.y, wb.z, wb.w};
#pragma unroll
                for (int i = 0; i < 4; ++i) {
                    a[i].x  = fmaf(wav[i], xv.x, a[i].x);
                    a[i].y  = fmaf(wav[i], xv.y, a[i].y);
                    a[i].z  = fmaf(wav[i], xv.z, a[i].z);
                    a[i].w  = fmaf(wav[i], xv.w, a[i].w);
                    bb[i].x = fmaf(wbv[i], xv.x, bb[i].x);
                    bb[i].y = fmaf(wbv[i], xv.y, bb[i].y);
                    bb[i].z = fmaf(wbv[i], xv.z, bb[i].z);
                    bb[i].w = fmaf(wbv[i], xv.w, bb[i].w);
                }
            }
            __syncthreads();
        }
        int n = n0 + tn4;
        if (ot == 0 && to4 == 0)
            *(float4*)&p.sq[b * NPTS + n] = s4;
#pragma unroll
        for (int i = 0; i < 4; ++i) {
            int o = o0 + to4 + i;
            size_t off = ((size_t)(b * p.Co + o)) * NPTS + n;
            *(float4*)&p.A[off] = a[i];
            *(float4*)&p.Bv[off] = bb[i];
        }
    } else {
        // ---------------- role B: banded gram partials
        int id2 = blockIdx.x - nABx;
        int chunk = id2 % p.nch; int rest = id2 / p.nch;
        int i = rest & 31; int b = rest >> 5;
        const float* xb = p.xin + (size_t)b * p.bstride;
        float* Xc = smem;
        int q = t >> 3;
        int wg = t & 7;
        float acc[28];
#pragma unroll
        for (int j = 0; j < 28; ++j) acc[j] = 0.f;
        for (int sub = 0; sub < 2; ++sub) {
            int c0 = chunk * 64 + sub * 32;
            if (c0 >= p.Cin) break;
            for (int e = t; e < 32 * CAND; e += 256) {
                int cc = e / CAND;
                int w  = e - cc * CAND;
                int wb = i - 3 + (w >> 5);
                wb = wb < 0 ? 0 : (wb > 31 ? 31 : wb);
                float v = xb[(size_t)(c0 + cc) * NPTS + wb * 32 + (w & 31)];
                if (p.applyBN) { float y = fmaf(v, shsc[c0 + cc], shsh[c0 + cc]); v = y >= 0.f ? y : 0.2f * y; }
                Xc[cc * CAND + w] = v;
            }
            __syncthreads();
            for (int cc = 0; cc < 32; ++cc) {
                float qv = Xc[cc * CAND + 96 + q];
                const float4* row = (const float4*)&Xc[cc * CAND + wg * 28];
#pragma unroll
                for (int j4 = 0; j4 < 7; ++j4) {
                    float4 v = row[j4];
                    acc[j4 * 4 + 0] = fmaf(qv, v.x, acc[j4 * 4 + 0]);
                    acc[j4 * 4 + 1] = fmaf(qv, v.y, acc[j4 * 4 + 1]);
                    acc[j4 * 4 + 2] = fmaf(qv, v.z, acc[j4 * 4 + 2]);
                    acc[j4 * 4 + 3] = fmaf(qv, v.w, acc[j4 * 4 + 3]);
                }
            }
            __syncthreads();
        }
        int n = i * 32 + q;
        size_t base = (((size_t)chunk * BATCH + b) * NPTS + n) * CAND + wg * 28;
        float4* outp = (float4*)&p.Dp[base];
#pragma unroll
        for (int j4 = 0; j4 < 7; ++j4)
            outp[j4] = make_float4(acc[j4 * 4], acc[j4 * 4 + 1], acc[j4 * 4 + 2], acc[j4 * 4 + 3]);
    }
}

// ================================================================ top-64 rank selection
__global__ __launch_bounds__(256) void kselect(const float* __restrict__ Dp, int nchunk,
                                               const float* __restrict__ sq,
                                               int* __restrict__ idxo) {
    __shared__ float Dsh[4][CAND];
    int t = threadIdx.x;
    int wv = t >> 6, l = t & 63;
    int b = blockIdx.y;
    int n = blockIdx.x * 4 + wv;
    int i = n >> 5;
    float sqn = sq[b * NPTS + n];
    float v[4];
    int wid[4];
#pragma unroll
    for (int j = 0; j < 4; ++j) {
        int w = l + 64 * j;
        wid[j] = w;
        if (w < CAND) {
            size_t off = ((size_t)b * NPTS + n) * CAND + w;
            float s = 0.f;
            for (int ch = 0; ch < nchunk; ++ch)
                s += Dp[off + (size_t)ch * (BATCH * NPTS * CAND)];
            int wb = i - 3 + (w >> 5);
            bool valid = (wb >= 0) && (wb < 32);
            int wbc = wb < 0 ? 0 : (wb > 31 ? 31 : wb);
            float d = 2.f * s - sqn - sq[b * NPTS + wbc * 32 + (w & 31)];
            v[j] = valid ? d : NEGV;
            Dsh[wv][w] = v[j];
        } else {
            v[j] = NEGV;
        }
    }
    __syncthreads();
    int cnt[4] = {0, 0, 0, 0};
    const float4* row = (const float4*)Dsh[wv];
    for (int w4 = 0; w4 < CAND / 4; ++w4) {
        float4 dv = row[w4];
        int wp = w4 * 4;
#pragma unroll
        for (int j = 0; j < 4; ++j) {
            cnt[j] += (dv.x > v[j]) || (dv.x == v[j] && (wp + 0) < wid[j]);
            cnt[j] += (dv.y > v[j]) || (dv.y == v[j] && (wp + 1) < wid[j]);
            cnt[j] += (dv.z > v[j]) || (dv.z == v[j] && (wp + 2) < wid[j]);
            cnt[j] += (dv.w > v[j]) || (dv.w == v[j] && (wp + 3) < wid[j]);
        }
    }
#pragma unroll
    for (int j = 0; j < 4; ++j)
        if (wid[j] < CAND && cnt[j] < KEFF)
            idxo[((size_t)b * NPTS + n) * KEFF + cnt[j]] = (i - 3) * 32 + wid[j];
}

// ================================================================ gather + max/S1/S2; maxY -> xconM (pre-BN)
__global__ __launch_bounds__(256) void kagg(const float* __restrict__ A, const float* __restrict__ Bv,
                                            const int* __restrict__ idx, int Co,
                                            float* __restrict__ xconM, int chOut,
                                            float* __restrict__ part) {
    __shared__ float Ash[NPTS];
    __shared__ float red[256];
    int o = blockIdx.x, b = blockIdx.y, t = threadIdx.x;
    size_t rowoff = ((size_t)(b * Co + o)) * NPTS;
    for (int r = 0; r < 4; ++r) Ash[r * 256 + t] = A[rowoff + r * 256 + t];
    __syncthreads();
    float sum = 0.f, sumsq = 0.f;
    for (int r = 0; r < 4; ++r) {
        int n = r * 256 + t;
        const int4* ip = (const int4*)&idx[((size_t)b * NPTS + n) * KEFF];
        float s1 = 0.f, s2 = 0.f, mx = -3.4e38f;
#pragma unroll
        for (int kk = 0; kk < KEFF / 4; ++kk) {
            int4 v4 = ip[kk];
            float a0 = Ash[v4.x], a1 = Ash[v4.y], a2 = Ash[v4.z], a3 = Ash[v4.w];
            s1 += a0 + a1 + a2 + a3;
            s2 += a0 * a0 + a1 * a1 + a2 * a2 + a3 * a3;
            mx = fmaxf(mx, fmaxf(fmaxf(a0, a1), fmaxf(a2, a3)));
        }
        float bv = Bv[rowoff + n];
        xconM[((size_t)b * 384 + chOut + o) * NPTS + n] = mx + bv;
        sum   += s1 + 64.f * bv;
        sumsq += s2 + 2.f * bv * s1 + 64.f * bv * bv;
    }
    red[t] = sum; __syncthreads();
    for (int s = 128; s > 0; s >>= 1) { if (t < s) red[t] += red[t + s]; __syncthreads(); }
    if (t == 0) part[((size_t)(b * Co + o)) * 2 + 0] = red[0];
    __syncthreads();
    red[t] = sumsq; __syncthreads();
    for (int s = 128; s > 0; s >>= 1) { if (t < s) red[t] += red[t + s]; __syncthreads(); }
    if (t == 0) part[((size_t)(b * Co + o)) * 2 + 1] = red[0];
}

// ================================================================ final GEMM with BN+leaky on load
struct FP {
    const float* part0; const float* part1; const float* part2; const float* part3;
    const float* g0; const float* g1; const float* g2; const float* g3;
    const float* be0; const float* be1; const float* be2; const float* be3;
};

__global__ __launch_bounds__(256) void kfinal(const float* __restrict__ xconM,
                                              const float* __restrict__ wlT, FP p,
                                              float* __restrict__ out) {
    __shared__ float Xs[2048];
    __shared__ float Wl[2176];
    __shared__ float shsc[384];
    __shared__ float shsh[384];
    int t = threadIdx.x;
    for (int ch = t; ch < 384; ch += 256) {
        const float* pl; const float* gl; const float* bl; int o, Col;
        if (ch < 128)      { pl = p.part0; gl = p.g0; bl = p.be0; o = ch;       Col = 128; }
        else if (ch < 256) { pl = p.part1; gl = p.g1; bl = p.be1; o = ch - 128; Col = 128; }
        else if (ch < 320) { pl = p.part2; gl = p.g2; bl = p.be2; o = ch - 256; Col = 64;  }
        else               { pl = p.part3; gl = p.g3; bl = p.be3; o = ch - 320; Col = 64;  }
        float s  = pl[o * 2]     + pl[(Col + o) * 2];
        float s2 = pl[o * 2 + 1] + pl[(Col + o) * 2 + 1];
        const float invc = 1.f / 131072.f;
        float mu = s * invc;
        float var = s2 * invc - mu * mu;
        float rs = rsqrtf(var + 1e-5f);
        float sc = gl[o] * rs;
        shsc[ch] = sc;
        shsh[ch] = bl[o] - mu * sc;
    }
    __syncthreads();
    int tn4 = (t & 15) * 4, to4 = (t >> 4) * 4;
    int n0 = blockIdx.x * 64, o0 = blockIdx.y * 64, b = blockIdx.z;
    float4 acc[4];
#pragma unroll
    for (int i = 0; i < 4; ++i) acc[i] = make_float4(0.f,0.f,0.f,0.f);
    for (int c0 = 0; c0 < 384; c0 += 32) {
        for (int e = t; e < 2048; e += 256) {
            int cc = e >> 6, nn = e & 63;
            float v = xconM[((size_t)b * 384 + c0 + cc) * NPTS + n0 + nn];
            float y = fmaf(v, shsc[c0 + cc], shsh[c0 + cc]);
            Xs[cc * 64 + nn] = y >= 0.f ? y : 0.2f * y;
        }
        for (int e = t; e < 2048; e += 256) {
            int cc = e >> 6, oo = e & 63;
            Wl[cc * 68 + oo] = wlT[(size_t)(c0 + cc) * 384 + o0 + oo];
        }
        __syncthreads();
#pragma unroll 4
        for (int cc = 0; cc < 32; ++cc) {
            float4 xv = *(const float4*)&Xs[cc * 64 + tn4];
            float4 wv = *(const float4*)&Wl[cc * 68 + to4];
            float wvv[4] = {wv.x, wv.y, wv.z, wv.w};
#pragma unroll
            for (int i = 0; i < 4; ++i) {
                acc[i].x = fmaf(wvv[i], xv.x, acc[i].x);
                acc[i].y = fmaf(wvv[i], xv.y, acc[i].y);
                acc[i].z = fmaf(wvv[i], xv.z, acc[i].z);
                acc[i].w = fmaf(wvv[i], xv.w, acc[i].w);
            }
        }
        __syncthreads();
    }
#pragma unroll
    for (int i = 0; i < 4; ++i)
        *(float4*)&out[((size_t)b * 384 + o0 + to4 + i) * NPTS + n0 + tn4] = acc[i];
}

extern "C" void kernel_launch(void* const* d_in, const int* in_sizes, int n_in,
                              void* d_out, int out_size, void* d_ws, size_t ws_size,
                              hipStream_t stream) {
    const float* x  = (const float*)d_in[0];
    const float* w[4]  = {(const float*)d_in[1], (const float*)d_in[4], (const float*)d_in[7], (const float*)d_in[10]};
    const float* g[4]  = {(const float*)d_in[2], (const float*)d_in[5], (const float*)d_in[8], (const float*)d_in[11]};
    const float* be[4] = {(const float*)d_in[3], (const float*)d_in[6], (const float*)d_in[9], (const float*)d_in[12]};
    const float* wl = (const float*)d_in[13];

    float* ws    = (float*)d_ws;
    float* xconM = ws;                       // 2*384*1024 = 786432 (pre-BN maxY concat)
    float* A     = xconM + 786432;           // 262144
    float* Bv    = A + 262144;               // 262144
    float* sq    = Bv + 262144;              // 2048
    float* Dp    = sq + 2048;                // 4*2*1024*224 = 1835008
    float* part  = Dp + 1835008;             // 4 layers * 512 = 2048
    float* wt    = part + 2048;              // 270336 (transposed weights)
    int*   idx   = (int*)(wt + 270336);      // 131072 ints
    // total ~13.6 MiB

    kprep<<<204, 256, 0, stream>>>(w[0], w[1], w[2], w[3], wl, wt);

    struct LC { const float* xin; int bstride; int Cin; int Co; int nch; int chOut;
                const float* wtA; const float* wtB; };
    LC L[4] = {
        { x,                  256 * 1024, 256, 128, 4, 0,   wt,          wt + 32768  },
        { xconM,              384 * 1024, 128, 128, 2, 128, wt + 65536,  wt + 81920  },
        { xconM + 128 * 1024, 384 * 1024, 128, 64,  2, 256, wt + 98304,  wt + 106496 },
        { xconM + 256 * 1024, 384 * 1024, 64,  64,  1, 320, wt + 114688, wt + 118784 },
    };

    for (int l = 0; l < 4; ++l) {
        GP gp;
        gp.xin = L[l].xin; gp.bstride = L[l].bstride; gp.Cin = L[l].Cin; gp.Co = L[l].Co;
        gp.nch = L[l].nch; gp.applyBN = (l > 0);
        gp.WtA = L[l].wtA; gp.WtB = L[l].wtB;
        gp.partPrev = (l > 0) ? part + (l - 1) * 512 : nullptr;
        gp.gPrev = (l > 0) ? g[l - 1] : nullptr;
        gp.bePrev = (l > 0) ? be[l - 1] : nullptr;
        gp.A = A; gp.Bv = Bv; gp.sq = sq; gp.Dp = Dp;
        int nAB = 16 * (L[l].Co >> 6) * BATCH;
        int nDist = L[l].nch * 32 * BATCH;
        kgemm  <<<nAB + nDist, 256, 0, stream>>>(gp);
        kselect<<<dim3(NPTS / 4, BATCH), 256, 0, stream>>>(Dp, L[l].nch, sq, idx);
        kagg   <<<dim3(L[l].Co, BATCH), 256, 0, stream>>>(A, Bv, idx, L[l].Co, xconM, L[l].chOut, part + l * 512);
    }

    FP fp;
    fp.part0 = part; fp.part1 = part + 512; fp.part2 = part + 1024; fp.part3 = part + 1536;
    fp.g0 = g[0]; fp.g1 = g[1]; fp.g2 = g[2]; fp.g3 = g[3];
    fp.be0 = be[0]; fp.be1 = be[1]; fp.be2 = be[2]; fp.be3 = be[3];
    kfinal<<<dim3(16, 6, BATCH), 256, 0, stream>>>(xconM, wt + 122880, fp, (float*)d_out);
}

// Round 5
// 404.089 us; speedup vs baseline: 1.7900x; 1.2212x over previous
//
#include <hip/hip_runtime.h>
#include <math.h>

#define NPTS 1024
#define CAND 224   // 7*32
#define KEFF 64
#define BATCH 2
#define NEGV -1e30f

// ================================================================ weight prep
// Transpose weights to c-major once per call. 32x32 tiles via LDS.
__global__ __launch_bounds__(256) void kprep(const float* __restrict__ w0, const float* __restrict__ w1,
                                             const float* __restrict__ w2, const float* __restrict__ w3,
                                             const float* __restrict__ wl, float* __restrict__ wt) {
    __shared__ float tA[32][33];
    __shared__ float tB[32][33];
    int id = blockIdx.x;
    int t = threadIdx.x;
    int row = t >> 5, col = t & 31;
    const float* W = w0; int Cin = 256, Co = 128; float* WtA = wt; float* WtB = wt + 32768;
    int tc = 0, to = 0; bool isWL = false;
    if (id < 32)      { int r = id;      tc = r >> 2; to = r & 3; }
    else if (id < 48) { W = w1; Cin = 128; Co = 128; WtA = wt + 65536;  WtB = wt + 81920;  int r = id - 32; tc = r >> 2; to = r & 3; }
    else if (id < 56) { W = w2; Cin = 128; Co = 64;  WtA = wt + 98304;  WtB = wt + 106496; int r = id - 48; tc = r >> 1; to = r & 1; }
    else if (id < 60) { W = w3; Cin = 64;  Co = 64;  WtA = wt + 114688; WtB = wt + 118784; int r = id - 56; tc = r >> 1; to = r & 1; }
    else { isWL = true; int r = id - 60; tc = r / 12; to = r % 12; }
    if (!isWL) {
#pragma unroll
        for (int r = 0; r < 4; ++r) {
            int o = to * 32 + row + r * 8;
            int c = tc * 32 + col;
            float va = W[(size_t)o * 2 * Cin + c];
            tA[row + r * 8][col] = va;
            tB[row + r * 8][col] = W[(size_t)o * 2 * Cin + Cin + c] - va;
        }
        __syncthreads();
#pragma unroll
        for (int r = 0; r < 4; ++r) {
            int c = tc * 32 + row + r * 8;
            int o = to * 32 + col;
            WtA[(size_t)c * Co + o] = tA[col][row + r * 8];
            WtB[(size_t)c * Co + o] = tB[col][row + r * 8];
        }
    } else {
        float* wlT = wt + 122880;
#pragma unroll
        for (int r = 0; r < 4; ++r) {
            int o = to * 32 + row + r * 8;
            int c = tc * 32 + col;
            tA[row + r * 8][col] = wl[(size_t)o * 384 + c];
        }
        __syncthreads();
#pragma unroll
        for (int r = 0; r < 4; ++r) {
            int c = tc * 32 + row + r * 8;
            int o = to * 32 + col;
            wlT[(size_t)c * 384 + o] = tA[col][row + r * 8];
        }
    }
}

// ================================================================ fused GEMM (A/Bv/sq) + banded gram
struct GP {
    const float* xin; int bstride; int Cin; int Co; int nch; int applyBN;
    const float* WtA; const float* WtB;
    const float* partPrev; const float* gPrev; const float* bePrev;
    float* A; float* Bv; float* sq; float* Dp;
};

__global__ __launch_bounds__(256) void kgemm(GP p) {
    __shared__ float smem[7168];      // roleA: Xs[0..2047], Wta[2048..4223], Wtb[4224..6399]; roleB: Xc[32][224]
    __shared__ float shsc[128];
    __shared__ float shsh[128];
    int t = threadIdx.x;
    if (p.applyBN && t < p.Cin) {
        const float* pp = p.partPrev;
        float s  = pp[t * 2]     + pp[(p.Cin + t) * 2];
        float s2 = pp[t * 2 + 1] + pp[(p.Cin + t) * 2 + 1];
        const float invc = 1.f / 131072.f;
        float mu = s * invc;
        float var = s2 * invc - mu * mu;
        float rs = rsqrtf(var + 1e-5f);
        float sc = p.gPrev[t] * rs;
        shsc[t] = sc;
        shsh[t] = p.bePrev[t] - mu * sc;
    }
    __syncthreads();
    int nABx = 16 * (p.Co >> 6) * BATCH;
    if ((int)blockIdx.x < nABx) {
        // ---------------- role A: A = WtA^T x, Bv = WtB^T x, sq
        int id = blockIdx.x;
        int nt = id & 15; int rest = id >> 4;
        int nOT = p.Co >> 6;
        int ot = rest % nOT; int b = rest / nOT;
        int tn4 = (t & 15) * 4, to4 = (t >> 4) * 4;
        int n0 = nt * 64, o0 = ot * 64;
        const float* xb = p.xin + (size_t)b * p.bstride + n0;
        float* Xs = smem; float* Wta = smem + 2048; float* Wtb = smem + 4224;
        float4 a[4], bb[4], s4;
#pragma unroll
        for (int i = 0; i < 4; ++i) { a[i] = make_float4(0.f,0.f,0.f,0.f); bb[i] = make_float4(0.f,0.f,0.f,0.f); }
        s4 = make_float4(0.f,0.f,0.f,0.f);
        int cc0 = t >> 6, nn0 = t & 63;   // e = t + k*256 -> cc = cc0 + k*4, nn/oo = nn0
        for (int c0 = 0; c0 < p.Cin; c0 += 32) {
            float rx[8], ra[8], rb[8];
#pragma unroll
            for (int k = 0; k < 8; ++k) {
                int cc = cc0 + k * 4;
                rx[k] = xb[(size_t)(c0 + cc) * NPTS + nn0];
                ra[k] = p.WtA[(size_t)(c0 + cc) * p.Co + o0 + nn0];
                rb[k] = p.WtB[(size_t)(c0 + cc) * p.Co + o0 + nn0];
            }
            if (p.applyBN) {
#pragma unroll
                for (int k = 0; k < 8; ++k) {
                    int cc = cc0 + k * 4;
                    float y = fmaf(rx[k], shsc[c0 + cc], shsh[c0 + cc]);
                    rx[k] = y >= 0.f ? y : 0.2f * y;
                }
            }
            __syncthreads();   // prev-tile compute done before overwrite
#pragma unroll
            for (int k = 0; k < 8; ++k) {
                int cc = cc0 + k * 4;
                Xs[cc * 64 + nn0] = rx[k];
                Wta[cc * 68 + nn0] = ra[k];
                Wtb[cc * 68 + nn0] = rb[k];
            }
            __syncthreads();
#pragma unroll 4
            for (int cc = 0; cc < 32; ++cc) {
                float4 xv = *(const float4*)&Xs[cc * 64 + tn4];
                float4 wa = *(const float4*)&Wta[cc * 68 + to4];
                float4 wb = *(const float4*)&Wtb[cc * 68 + to4];
                s4.x = fmaf(xv.x, xv.x, s4.x);
                s4.y = fmaf(xv.y, xv.y, s4.y);
                s4.z = fmaf(xv.z, xv.z, s4.z);
                s4.w = fmaf(xv.w, xv.w, s4.w);
                float wav[4] = {wa.x, wa.y, wa.z, wa.w};
                float wbv[4] = {wb.x, wb.y, wb.z, wb.w};
#pragma unroll
                for (int i = 0; i < 4; ++i) {
                    a[i].x  = fmaf(wav[i], xv.x, a[i].x);
                    a[i].y  = fmaf(wav[i], xv.y, a[i].y);
                    a[i].z  = fmaf(wav[i], xv.z, a[i].z);
                    a[i].w  = fmaf(wav[i], xv.w, a[i].w);
                    bb[i].x = fmaf(wbv[i], xv.x, bb[i].x);
                    bb[i].y = fmaf(wbv[i], xv.y, bb[i].y);
                    bb[i].z = fmaf(wbv[i], xv.z, bb[i].z);
                    bb[i].w = fmaf(wbv[i], xv.w, bb[i].w);
                }
            }
        }
        int n = n0 + tn4;
        if (ot == 0 && to4 == 0)
            *(float4*)&p.sq[b * NPTS + n] = s4;
#pragma unroll
        for (int i = 0; i < 4; ++i) {
            int o = o0 + to4 + i;
            size_t off = ((size_t)(b * p.Co + o)) * NPTS + n;
            *(float4*)&p.A[off] = a[i];
            *(float4*)&p.Bv[off] = bb[i];
        }
    } else {
        // ---------------- role B: banded gram partials
        int id2 = blockIdx.x - nABx;
        int chunk = id2 % p.nch; int rest = id2 / p.nch;
        int i = rest & 31; int b = rest >> 5;
        const float* xb = p.xin + (size_t)b * p.bstride;
        float* Xc = smem;
        int q = t >> 3;
        int wg = t & 7;
        float acc[28];
#pragma unroll
        for (int j = 0; j < 28; ++j) acc[j] = 0.f;
        for (int sub = 0; sub < 2; ++sub) {
            int c0 = chunk * 64 + sub * 32;
            if (c0 >= p.Cin) break;
            float r[28];
            int rcc[28], rw[28];
#pragma unroll
            for (int k = 0; k < 28; ++k) {
                int e = t + k * 256;
                int cc = e / CAND;
                int w  = e - cc * CAND;
                rcc[k] = cc; rw[k] = w;
                int wb = i - 3 + (w >> 5);
                wb = wb < 0 ? 0 : (wb > 31 ? 31 : wb);
                r[k] = xb[(size_t)(c0 + cc) * NPTS + wb * 32 + (w & 31)];
            }
            if (p.applyBN) {
#pragma unroll
                for (int k = 0; k < 28; ++k) {
                    float y = fmaf(r[k], shsc[c0 + rcc[k]], shsh[c0 + rcc[k]]);
                    r[k] = y >= 0.f ? y : 0.2f * y;
                }
            }
            __syncthreads();
#pragma unroll
            for (int k = 0; k < 28; ++k)
                Xc[rcc[k] * CAND + rw[k]] = r[k];
            __syncthreads();
            for (int cc = 0; cc < 32; ++cc) {
                float qv = Xc[cc * CAND + 96 + q];
                const float4* row = (const float4*)&Xc[cc * CAND + wg * 28];
#pragma unroll
                for (int j4 = 0; j4 < 7; ++j4) {
                    float4 v = row[j4];
                    acc[j4 * 4 + 0] = fmaf(qv, v.x, acc[j4 * 4 + 0]);
                    acc[j4 * 4 + 1] = fmaf(qv, v.y, acc[j4 * 4 + 1]);
                    acc[j4 * 4 + 2] = fmaf(qv, v.z, acc[j4 * 4 + 2]);
                    acc[j4 * 4 + 3] = fmaf(qv, v.w, acc[j4 * 4 + 3]);
                }
            }
        }
        int n = i * 32 + q;
        size_t base = (((size_t)chunk * BATCH + b) * NPTS + n) * CAND + wg * 28;
        float4* outp = (float4*)&p.Dp[base];
#pragma unroll
        for (int j4 = 0; j4 < 7; ++j4)
            outp[j4] = make_float4(acc[j4 * 4], acc[j4 * 4 + 1], acc[j4 * 4 + 2], acc[j4 * 4 + 3]);
    }
}

// ================================================================ top-64 rank selection
__global__ __launch_bounds__(256) void kselect(const float* __restrict__ Dp, int nchunk,
                                               const float* __restrict__ sq,
                                               int* __restrict__ idxo) {
    __shared__ float Dsh[4][CAND];
    int t = threadIdx.x;
    int wv = t >> 6, l = t & 63;
    int b = blockIdx.y;
    int n = blockIdx.x * 4 + wv;
    int i = n >> 5;
    float sqn = sq[b * NPTS + n];
    float v[4];
    int wid[4];
#pragma unroll
    for (int j = 0; j < 4; ++j) {
        int w = l + 64 * j;
        wid[j] = w;
        if (w < CAND) {
            size_t off = ((size_t)b * NPTS + n) * CAND + w;
            float s = 0.f;
            for (int ch = 0; ch < nchunk; ++ch)
                s += Dp[off + (size_t)ch * (BATCH * NPTS * CAND)];
            int wb = i - 3 + (w >> 5);
            bool valid = (wb >= 0) && (wb < 32);
            int wbc = wb < 0 ? 0 : (wb > 31 ? 31 : wb);
            float d = 2.f * s - sqn - sq[b * NPTS + wbc * 32 + (w & 31)];
            v[j] = valid ? d : NEGV;
            Dsh[wv][w] = v[j];
        } else {
            v[j] = NEGV;
        }
    }
    __syncthreads();
    int cnt[4] = {0, 0, 0, 0};
    const float4* row = (const float4*)Dsh[wv];
    for (int w4 = 0; w4 < CAND / 4; ++w4) {
        float4 dv = row[w4];
        int wp = w4 * 4;
#pragma unroll
        for (int j = 0; j < 4; ++j) {
            cnt[j] += (dv.x > v[j]) || (dv.x == v[j] && (wp + 0) < wid[j]);
            cnt[j] += (dv.y > v[j]) || (dv.y == v[j] && (wp + 1) < wid[j]);
            cnt[j] += (dv.z > v[j]) || (dv.z == v[j] && (wp + 2) < wid[j]);
            cnt[j] += (dv.w > v[j]) || (dv.w == v[j] && (wp + 3) < wid[j]);
        }
    }
#pragma unroll
    for (int j = 0; j < 4; ++j)
        if (wid[j] < CAND && cnt[j] < KEFF)
            idxo[((size_t)b * NPTS + n) * KEFF + cnt[j]] = (i - 3) * 32 + wid[j];
}

// ================================================================ gather + max/S1/S2; maxY -> xconM (pre-BN)
__global__ __launch_bounds__(256) void kagg(const float* __restrict__ A, const float* __restrict__ Bv,
                                            const int* __restrict__ idx, int Co,
                                            float* __restrict__ xconM, int chOut,
                                            float* __restrict__ part) {
    __shared__ float Ash[NPTS];
    __shared__ float red[256];
    int o = blockIdx.x, b = blockIdx.y, t = threadIdx.x;
    size_t rowoff = ((size_t)(b * Co + o)) * NPTS;
    {
        float rA[4];
#pragma unroll
        for (int r = 0; r < 4; ++r) rA[r] = A[rowoff + r * 256 + t];
#pragma unroll
        for (int r = 0; r < 4; ++r) Ash[r * 256 + t] = rA[r];
    }
    __syncthreads();
    float sum = 0.f, sumsq = 0.f;
    for (int r = 0; r < 4; ++r) {
        int n = r * 256 + t;
        const int4* ip = (const int4*)&idx[((size_t)b * NPTS + n) * KEFF];
        float s1 = 0.f, s2 = 0.f, mx = -3.4e38f;
#pragma unroll
        for (int kk = 0; kk < KEFF / 4; ++kk) {
            int4 v4 = ip[kk];
            float a0 = Ash[v4.x], a1 = Ash[v4.y], a2 = Ash[v4.z], a3 = Ash[v4.w];
            s1 += a0 + a1 + a2 + a3;
            s2 += a0 * a0 + a1 * a1 + a2 * a2 + a3 * a3;
            mx = fmaxf(mx, fmaxf(fmaxf(a0, a1), fmaxf(a2, a3)));
        }
        float bv = Bv[rowoff + n];
        xconM[((size_t)b * 384 + chOut + o) * NPTS + n] = mx + bv;
        sum   += s1 + 64.f * bv;
        sumsq += s2 + 2.f * bv * s1 + 64.f * bv * bv;
    }
    red[t] = sum; __syncthreads();
    for (int s = 128; s > 0; s >>= 1) { if (t < s) red[t] += red[t + s]; __syncthreads(); }
    if (t == 0) part[((size_t)(b * Co + o)) * 2 + 0] = red[0];
    __syncthreads();
    red[t] = sumsq; __syncthreads();
    for (int s = 128; s > 0; s >>= 1) { if (t < s) red[t] += red[t + s]; __syncthreads(); }
    if (t == 0) part[((size_t)(b * Co + o)) * 2 + 1] = red[0];
}

// ================================================================ final GEMM with BN+leaky on load
struct FP {
    const float* part0; const float* part1; const float* part2; const float* part3;
    const float* g0; const float* g1; const float* g2; const float* g3;
    const float* be0; const float* be1; const float* be2; const float* be3;
};

__global__ __launch_bounds__(256) void kfinal(const float* __restrict__ xconM,
                                              const float* __restrict__ wlT, FP p,
                                              float* __restrict__ out) {
    __shared__ float Xs[2048];
    __shared__ float Wl[2176];
    __shared__ float shsc[384];
    __shared__ float shsh[384];
    int t = threadIdx.x;
    for (int ch = t; ch < 384; ch += 256) {
        const float* pl; const float* gl; const float* bl; int o, Col;
        if (ch < 128)      { pl = p.part0; gl = p.g0; bl = p.be0; o = ch;       Col = 128; }
        else if (ch < 256) { pl = p.part1; gl = p.g1; bl = p.be1; o = ch - 128; Col = 128; }
        else if (ch < 320) { pl = p.part2; gl = p.g2; bl = p.be2; o = ch - 256; Col = 64;  }
        else               { pl = p.part3; gl = p.g3; bl = p.be3; o = ch - 320; Col = 64;  }
        float s  = pl[o * 2]     + pl[(Col + o) * 2];
        float s2 = pl[o * 2 + 1] + pl[(Col + o) * 2 + 1];
        const float invc = 1.f / 131072.f;
        float mu = s * invc;
        float var = s2 * invc - mu * mu;
        float rs = rsqrtf(var + 1e-5f);
        float sc = gl[o] * rs;
        shsc[ch] = sc;
        shsh[ch] = bl[o] - mu * sc;
    }
    __syncthreads();
    int tn4 = (t & 15) * 4, to4 = (t >> 4) * 4;
    int n0 = blockIdx.x * 64, o0 = blockIdx.y * 64, b = blockIdx.z;
    int cc0 = t >> 6, nn0 = t & 63;
    float4 acc[4];
#pragma unroll
    for (int i = 0; i < 4; ++i) acc[i] = make_float4(0.f,0.f,0.f,0.f);
    for (int c0 = 0; c0 < 384; c0 += 32) {
        float rx[8], rw[8];
#pragma unroll
        for (int k = 0; k < 8; ++k) {
            int cc = cc0 + k * 4;
            rx[k] = xconM[((size_t)b * 384 + c0 + cc) * NPTS + n0 + nn0];
            rw[k] = wlT[(size_t)(c0 + cc) * 384 + o0 + nn0];
        }
#pragma unroll
        for (int k = 0; k < 8; ++k) {
            int cc = cc0 + k * 4;
            float y = fmaf(rx[k], shsc[c0 + cc], shsh[c0 + cc]);
            rx[k] = y >= 0.f ? y : 0.2f * y;
        }
        __syncthreads();
#pragma unroll
        for (int k = 0; k < 8; ++k) {
            int cc = cc0 + k * 4;
            Xs[cc * 64 + nn0] = rx[k];
            Wl[cc * 68 + nn0] = rw[k];
        }
        __syncthreads();
#pragma unroll 4
        for (int cc = 0; cc < 32; ++cc) {
            float4 xv = *(const float4*)&Xs[cc * 64 + tn4];
            float4 wv = *(const float4*)&Wl[cc * 68 + to4];
            float wvv[4] = {wv.x, wv.y, wv.z, wv.w};
#pragma unroll
            for (int i = 0; i < 4; ++i) {
                acc[i].x = fmaf(wvv[i], xv.x, acc[i].x);
                acc[i].y = fmaf(wvv[i], xv.y, acc[i].y);
                acc[i].z = fmaf(wvv[i], xv.z, acc[i].z);
                acc[i].w = fmaf(wvv[i], xv.w, acc[i].w);
            }
        }
    }
#pragma unroll
    for (int i = 0; i < 4; ++i)
        *(float4*)&out[((size_t)b * 384 + o0 + to4 + i) * NPTS + n0 + tn4] = acc[i];
}

extern "C" void kernel_launch(void* const* d_in, const int* in_sizes, int n_in,
                              void* d_out, int out_size, void* d_ws, size_t ws_size,
                              hipStream_t stream) {
    const float* x  = (const float*)d_in[0];
    const float* w[4]  = {(const float*)d_in[1], (const float*)d_in[4], (const float*)d_in[7], (const float*)d_in[10]};
    const float* g[4]  = {(const float*)d_in[2], (const float*)d_in[5], (const float*)d_in[8], (const float*)d_in[11]};
    const float* be[4] = {(const float*)d_in[3], (const float*)d_in[6], (const float*)d_in[9], (const float*)d_in[12]};
    const float* wl = (const float*)d_in[13];

    float* ws    = (float*)d_ws;
    float* xconM = ws;                       // 2*384*1024 = 786432 (pre-BN maxY concat)
    float* A     = xconM + 786432;           // 262144
    float* Bv    = A + 262144;               // 262144
    float* sq    = Bv + 262144;              // 2048
    float* Dp    = sq + 2048;                // 4*2*1024*224 = 1835008
    float* part  = Dp + 1835008;             // 4 layers * 512 = 2048
    float* wt    = part + 2048;              // 270336 (transposed weights)
    int*   idx   = (int*)(wt + 270336);      // 131072 ints

    kprep<<<204, 256, 0, stream>>>(w[0], w[1], w[2], w[3], wl, wt);

    struct LC { const float* xin; int bstride; int Cin; int Co; int nch; int chOut;
                const float* wtA; const float* wtB; };
    LC L[4] = {
        { x,                  256 * 1024, 256, 128, 4, 0,   wt,          wt + 32768  },
        { xconM,              384 * 1024, 128, 128, 2, 128, wt + 65536,  wt + 81920  },
        { xconM + 128 * 1024, 384 * 1024, 128, 64,  2, 256, wt + 98304,  wt + 106496 },
        { xconM + 256 * 1024, 384 * 1024, 64,  64,  1, 320, wt + 114688, wt + 118784 },
    };

    for (int l = 0; l < 4; ++l) {
        GP gp;
        gp.xin = L[l].xin; gp.bstride = L[l].bstride; gp.Cin = L[l].Cin; gp.Co = L[l].Co;
        gp.nch = L[l].nch; gp.applyBN = (l > 0);
        gp.WtA = L[l].wtA; gp.WtB = L[l].wtB;
        gp.partPrev = (l > 0) ? part + (l - 1) * 512 : nullptr;
        gp.gPrev = (l > 0) ? g[l - 1] : nullptr;
        gp.bePrev = (l > 0) ? be[l - 1] : nullptr;
        gp.A = A; gp.Bv = Bv; gp.sq = sq; gp.Dp = Dp;
        int nAB = 16 * (L[l].Co >> 6) * BATCH;
        int nDist = L[l].nch * 32 * BATCH;
        kgemm  <<<nAB + nDist, 256, 0, stream>>>(gp);
        kselect<<<dim3(NPTS / 4, BATCH), 256, 0, stream>>>(Dp, L[l].nch, sq, idx);
        kagg   <<<dim3(L[l].Co, BATCH), 256, 0, stream>>>(A, Bv, idx, L[l].Co, xconM, L[l].chOut, part + l * 512);
    }

    FP fp;
    fp.part0 = part; fp.part1 = part + 512; fp.part2 = part + 1024; fp.part3 = part + 1536;
    fp.g0 = g[0]; fp.g1 = g[1]; fp.g2 = g[2]; fp.g3 = g[3];
    fp.be0 = be[0]; fp.be1 = be[1]; fp.be2 = be[2]; fp.be3 = be[3];
    kfinal<<<dim3(16, 6, BATCH), 256, 0, stream>>>(xconM, wt + 122880, fp, (float*)d_out);
}

// Round 6
// 393.099 us; speedup vs baseline: 1.8401x; 1.0280x over previous
//
#include <hip/hip_runtime.h>
#include <math.h>

#define NPTS 1024
#define CAND 224   // 7*32
#define KEFF 64
#define BATCH 2
#define NEGV -1e30f

// ================================================================ weight prep
// Transpose weights to c-major once per call. 32x32 tiles via LDS.
__global__ __launch_bounds__(256) void kprep(const float* __restrict__ w0, const float* __restrict__ w1,
                                             const float* __restrict__ w2, const float* __restrict__ w3,
                                             const float* __restrict__ wl, float* __restrict__ wt) {
    __shared__ float tA[32][33];
    __shared__ float tB[32][33];
    int id = blockIdx.x;
    int t = threadIdx.x;
    int row = t >> 5, col = t & 31;
    const float* W = w0; int Cin = 256, Co = 128; float* WtA = wt; float* WtB = wt + 32768;
    int tc = 0, to = 0; bool isWL = false;
    if (id < 32)      { int r = id;      tc = r >> 2; to = r & 3; }
    else if (id < 48) { W = w1; Cin = 128; Co = 128; WtA = wt + 65536;  WtB = wt + 81920;  int r = id - 32; tc = r >> 2; to = r & 3; }
    else if (id < 56) { W = w2; Cin = 128; Co = 64;  WtA = wt + 98304;  WtB = wt + 106496; int r = id - 48; tc = r >> 1; to = r & 1; }
    else if (id < 60) { W = w3; Cin = 64;  Co = 64;  WtA = wt + 114688; WtB = wt + 118784; int r = id - 56; tc = r >> 1; to = r & 1; }
    else { isWL = true; int r = id - 60; tc = r / 12; to = r % 12; }
    if (!isWL) {
#pragma unroll
        for (int r = 0; r < 4; ++r) {
            int o = to * 32 + row + r * 8;
            int c = tc * 32 + col;
            float va = W[(size_t)o * 2 * Cin + c];
            tA[row + r * 8][col] = va;
            tB[row + r * 8][col] = W[(size_t)o * 2 * Cin + Cin + c] - va;
        }
        __syncthreads();
#pragma unroll
        for (int r = 0; r < 4; ++r) {
            int c = tc * 32 + row + r * 8;
            int o = to * 32 + col;
            WtA[(size_t)c * Co + o] = tA[col][row + r * 8];
            WtB[(size_t)c * Co + o] = tB[col][row + r * 8];
        }
    } else {
        float* wlT = wt + 122880;
#pragma unroll
        for (int r = 0; r < 4; ++r) {
            int o = to * 32 + row + r * 8;
            int c = tc * 32 + col;
            tA[row + r * 8][col] = wl[(size_t)o * 384 + c];
        }
        __syncthreads();
#pragma unroll
        for (int r = 0; r < 4; ++r) {
            int c = tc * 32 + row + r * 8;
            int o = to * 32 + col;
            wlT[(size_t)c * 384 + o] = tA[col][row + r * 8];
        }
    }
}

// ================================================================ fused GEMM (A/Bv/sq) + banded gram
struct GP {
    const float* xin; int bstride; int Cin; int Co; int nch; int applyBN;
    const float* WtA; const float* WtB;
    const float* partPrev; const float* gPrev; const float* bePrev;
    float* A; float* Bv; float* sq; float* Dp;
};

__global__ __launch_bounds__(256) void kgemm(GP p) {
    __shared__ float smem[7168];      // roleA: Xs[0..2047], Wta[2048..4223], Wtb[4224..6399]; roleB: Xc[32][224]
    __shared__ float shsc[128];
    __shared__ float shsh[128];
    int t = threadIdx.x;
    if (p.applyBN && t < p.Cin) {
        const float* pp = p.partPrev;
        float s  = pp[t * 2]     + pp[(p.Cin + t) * 2];
        float s2 = pp[t * 2 + 1] + pp[(p.Cin + t) * 2 + 1];
        const float invc = 1.f / 131072.f;
        float mu = s * invc;
        float var = s2 * invc - mu * mu;
        float rs = rsqrtf(var + 1e-5f);
        float sc = p.gPrev[t] * rs;
        shsc[t] = sc;
        shsh[t] = p.bePrev[t] - mu * sc;
    }
    __syncthreads();
    int nABx = 16 * (p.Co >> 6) * BATCH;
    if ((int)blockIdx.x < nABx) {
        // ---------------- role A: A = WtA^T x, Bv = WtB^T x, sq
        int id = blockIdx.x;
        int nt = id & 15; int rest = id >> 4;
        int nOT = p.Co >> 6;
        int ot = rest % nOT; int b = rest / nOT;
        int tn4 = (t & 15) * 4, to4 = (t >> 4) * 4;
        int n0 = nt * 64, o0 = ot * 64;
        const float* xb = p.xin + (size_t)b * p.bstride + n0;
        float* Xs = smem; float* Wta = smem + 2048; float* Wtb = smem + 4224;
        float4 a[4], bb[4], s4;
#pragma unroll
        for (int i = 0; i < 4; ++i) { a[i] = make_float4(0.f,0.f,0.f,0.f); bb[i] = make_float4(0.f,0.f,0.f,0.f); }
        s4 = make_float4(0.f,0.f,0.f,0.f);
        int cc0 = t >> 6, nn0 = t & 63;   // e = t + k*256 -> cc = cc0 + k*4, nn/oo = nn0
        for (int c0 = 0; c0 < p.Cin; c0 += 32) {
            float rx[8], ra[8], rb[8];
#pragma unroll
            for (int k = 0; k < 8; ++k) {
                int cc = cc0 + k * 4;
                rx[k] = xb[(size_t)(c0 + cc) * NPTS + nn0];
                ra[k] = p.WtA[(size_t)(c0 + cc) * p.Co + o0 + nn0];
                rb[k] = p.WtB[(size_t)(c0 + cc) * p.Co + o0 + nn0];
            }
            if (p.applyBN) {
#pragma unroll
                for (int k = 0; k < 8; ++k) {
                    int cc = cc0 + k * 4;
                    float y = fmaf(rx[k], shsc[c0 + cc], shsh[c0 + cc]);
                    rx[k] = y >= 0.f ? y : 0.2f * y;
                }
            }
            __syncthreads();   // prev-tile compute done before overwrite
#pragma unroll
            for (int k = 0; k < 8; ++k) {
                int cc = cc0 + k * 4;
                Xs[cc * 64 + nn0] = rx[k];
                Wta[cc * 68 + nn0] = ra[k];
                Wtb[cc * 68 + nn0] = rb[k];
            }
            __syncthreads();
#pragma unroll 4
            for (int cc = 0; cc < 32; ++cc) {
                float4 xv = *(const float4*)&Xs[cc * 64 + tn4];
                float4 wa = *(const float4*)&Wta[cc * 68 + to4];
                float4 wb = *(const float4*)&Wtb[cc * 68 + to4];
                s4.x = fmaf(xv.x, xv.x, s4.x);
                s4.y = fmaf(xv.y, xv.y, s4.y);
                s4.z = fmaf(xv.z, xv.z, s4.z);
                s4.w = fmaf(xv.w, xv.w, s4.w);
                float wav[4] = {wa.x, wa.y, wa.z, wa.w};
                float wbv[4] = {wb.x, wb.y, wb.z, wb.w};
#pragma unroll
                for (int i = 0; i < 4; ++i) {
                    a[i].x  = fmaf(wav[i], xv.x, a[i].x);
                    a[i].y  = fmaf(wav[i], xv.y, a[i].y);
                    a[i].z  = fmaf(wav[i], xv.z, a[i].z);
                    a[i].w  = fmaf(wav[i], xv.w, a[i].w);
                    bb[i].x = fmaf(wbv[i], xv.x, bb[i].x);
                    bb[i].y = fmaf(wbv[i], xv.y, bb[i].y);
                    bb[i].z = fmaf(wbv[i], xv.z, bb[i].z);
                    bb[i].w = fmaf(wbv[i], xv.w, bb[i].w);
                }
            }
        }
        int n = n0 + tn4;
        if (ot == 0 && to4 == 0)
            *(float4*)&p.sq[b * NPTS + n] = s4;
#pragma unroll
        for (int i = 0; i < 4; ++i) {
            int o = o0 + to4 + i;
            size_t off = ((size_t)(b * p.Co + o)) * NPTS + n;
            *(float4*)&p.A[off] = a[i];
            *(float4*)&p.Bv[off] = bb[i];
        }
    } else {
        // ---------------- role B: banded gram partials
        int id2 = blockIdx.x - nABx;
        int chunk = id2 % p.nch; int rest = id2 / p.nch;
        int i = rest & 31; int b = rest >> 5;
        const float* xb = p.xin + (size_t)b * p.bstride;
        float* Xc = smem;
        int q = t >> 3;
        int wg = t & 7;
        float acc[28];
#pragma unroll
        for (int j = 0; j < 28; ++j) acc[j] = 0.f;
        for (int sub = 0; sub < 2; ++sub) {
            int c0 = chunk * 64 + sub * 32;
            if (c0 >= p.Cin) break;
            float r[28];
            int rcc[28], rw[28];
#pragma unroll
            for (int k = 0; k < 28; ++k) {
                int e = t + k * 256;
                int cc = e / CAND;
                int w  = e - cc * CAND;
                rcc[k] = cc; rw[k] = w;
                int wb = i - 3 + (w >> 5);
                wb = wb < 0 ? 0 : (wb > 31 ? 31 : wb);
                r[k] = xb[(size_t)(c0 + cc) * NPTS + wb * 32 + (w & 31)];
            }
            if (p.applyBN) {
#pragma unroll
                for (int k = 0; k < 28; ++k) {
                    float y = fmaf(r[k], shsc[c0 + rcc[k]], shsh[c0 + rcc[k]]);
                    r[k] = y >= 0.f ? y : 0.2f * y;
                }
            }
            __syncthreads();
#pragma unroll
            for (int k = 0; k < 28; ++k)
                Xc[rcc[k] * CAND + rw[k]] = r[k];
            __syncthreads();
            for (int cc = 0; cc < 32; ++cc) {
                float qv = Xc[cc * CAND + 96 + q];
                const float4* row = (const float4*)&Xc[cc * CAND + wg * 28];
#pragma unroll
                for (int j4 = 0; j4 < 7; ++j4) {
                    float4 v = row[j4];
                    acc[j4 * 4 + 0] = fmaf(qv, v.x, acc[j4 * 4 + 0]);
                    acc[j4 * 4 + 1] = fmaf(qv, v.y, acc[j4 * 4 + 1]);
                    acc[j4 * 4 + 2] = fmaf(qv, v.z, acc[j4 * 4 + 2]);
                    acc[j4 * 4 + 3] = fmaf(qv, v.w, acc[j4 * 4 + 3]);
                }
            }
        }
        int n = i * 32 + q;
        size_t base = (((size_t)chunk * BATCH + b) * NPTS + n) * CAND + wg * 28;
        float4* outp = (float4*)&p.Dp[base];
#pragma unroll
        for (int j4 = 0; j4 < 7; ++j4)
            outp[j4] = make_float4(acc[j4 * 4], acc[j4 * 4 + 1], acc[j4 * 4 + 2], acc[j4 * 4 + 3]);
    }
}

// ================================================================ top-64 rank selection (NCH compile-time)
template<int NCH>
__global__ __launch_bounds__(256) void kselect(const float* __restrict__ Dp,
                                               const float* __restrict__ sq,
                                               int* __restrict__ idxo) {
    __shared__ float Dsh[4][CAND];
    int t = threadIdx.x;
    int wv = t >> 6, l = t & 63;
    int b = blockIdx.y;
    int n = blockIdx.x * 4 + wv;
    int i = n >> 5;
    float sqn = sq[b * NPTS + n];
    float pr[4][NCH];
    float sqw[4];
    float v[4];
    // phase 1a: issue ALL loads (independent) before any combine
#pragma unroll
    for (int j = 0; j < 4; ++j) {
        int w = l + 64 * j;
        if (w < CAND) {
            size_t off = ((size_t)b * NPTS + n) * CAND + w;
#pragma unroll
            for (int ch = 0; ch < NCH; ++ch)
                pr[j][ch] = Dp[off + (size_t)ch * (BATCH * NPTS * CAND)];
            int wb = i - 3 + (w >> 5);
            int wbc = wb < 0 ? 0 : (wb > 31 ? 31 : wb);
            sqw[j] = sq[b * NPTS + wbc * 32 + (w & 31)];
        }
    }
    // phase 1b: combine (ascending ch order preserved -> bit-identical)
#pragma unroll
    for (int j = 0; j < 4; ++j) {
        int w = l + 64 * j;
        if (w < CAND) {
            float s = 0.f;
#pragma unroll
            for (int ch = 0; ch < NCH; ++ch) s += pr[j][ch];
            int wb = i - 3 + (w >> 5);
            bool valid = (wb >= 0) && (wb < 32);
            float d = 2.f * s - sqn - sqw[j];
            v[j] = valid ? d : NEGV;
            Dsh[wv][w] = v[j];
        } else {
            v[j] = NEGV;
        }
    }
    __syncthreads();
    int wid[4];
#pragma unroll
    for (int j = 0; j < 4; ++j) wid[j] = l + 64 * j;
    int cnt[4] = {0, 0, 0, 0};
    const float4* row = (const float4*)Dsh[wv];
    for (int w4 = 0; w4 < CAND / 4; ++w4) {
        float4 dv = row[w4];
        int wp = w4 * 4;
#pragma unroll
        for (int j = 0; j < 4; ++j) {
            cnt[j] += (dv.x > v[j]) || (dv.x == v[j] && (wp + 0) < wid[j]);
            cnt[j] += (dv.y > v[j]) || (dv.y == v[j] && (wp + 1) < wid[j]);
            cnt[j] += (dv.z > v[j]) || (dv.z == v[j] && (wp + 2) < wid[j]);
            cnt[j] += (dv.w > v[j]) || (dv.w == v[j] && (wp + 3) < wid[j]);
        }
    }
#pragma unroll
    for (int j = 0; j < 4; ++j)
        if (wid[j] < CAND && cnt[j] < KEFF)
            idxo[((size_t)b * NPTS + n) * KEFF + cnt[j]] = (i - 3) * 32 + wid[j];
}

// ================================================================ gather + max/S1/S2; maxY -> xconM (pre-BN)
__global__ __launch_bounds__(256) void kagg(const float* __restrict__ A, const float* __restrict__ Bv,
                                            const int* __restrict__ idx, int Co,
                                            float* __restrict__ xconM, int chOut,
                                            float* __restrict__ part) {
    __shared__ float Ash[NPTS];
    __shared__ float red[256];
    int o = blockIdx.x, b = blockIdx.y, t = threadIdx.x;
    size_t rowoff = ((size_t)(b * Co + o)) * NPTS;
    {
        float rA[4];
#pragma unroll
        for (int r = 0; r < 4; ++r) rA[r] = A[rowoff + r * 256 + t];
#pragma unroll
        for (int r = 0; r < 4; ++r) Ash[r * 256 + t] = rA[r];
    }
    __syncthreads();
    float sum = 0.f, sumsq = 0.f;
    for (int r = 0; r < 4; ++r) {
        int n = r * 256 + t;
        const int4* ip = (const int4*)&idx[((size_t)b * NPTS + n) * KEFF];
        float s1 = 0.f, s2 = 0.f, mx = -3.4e38f;
#pragma unroll
        for (int kk = 0; kk < KEFF / 4; ++kk) {
            int4 v4 = ip[kk];
            float a0 = Ash[v4.x], a1 = Ash[v4.y], a2 = Ash[v4.z], a3 = Ash[v4.w];
            s1 += a0 + a1 + a2 + a3;
            s2 += a0 * a0 + a1 * a1 + a2 * a2 + a3 * a3;
            mx = fmaxf(mx, fmaxf(fmaxf(a0, a1), fmaxf(a2, a3)));
        }
        float bv = Bv[rowoff + n];
        xconM[((size_t)b * 384 + chOut + o) * NPTS + n] = mx + bv;
        sum   += s1 + 64.f * bv;
        sumsq += s2 + 2.f * bv * s1 + 64.f * bv * bv;
    }
    red[t] = sum; __syncthreads();
    for (int s = 128; s > 0; s >>= 1) { if (t < s) red[t] += red[t + s]; __syncthreads(); }
    if (t == 0) part[((size_t)(b * Co + o)) * 2 + 0] = red[0];
    __syncthreads();
    red[t] = sumsq; __syncthreads();
    for (int s = 128; s > 0; s >>= 1) { if (t < s) red[t] += red[t + s]; __syncthreads(); }
    if (t == 0) part[((size_t)(b * Co + o)) * 2 + 1] = red[0];
}

// ================================================================ final GEMM with BN+leaky on load
struct FP {
    const float* part0; const float* part1; const float* part2; const float* part3;
    const float* g0; const float* g1; const float* g2; const float* g3;
    const float* be0; const float* be1; const float* be2; const float* be3;
};

__global__ __launch_bounds__(256) void kfinal(const float* __restrict__ xconM,
                                              const float* __restrict__ wlT, FP p,
                                              float* __restrict__ out) {
    __shared__ float Xs[2048];
    __shared__ float Wl[2176];
    __shared__ float shsc[384];
    __shared__ float shsh[384];
    int t = threadIdx.x;
    for (int ch = t; ch < 384; ch += 256) {
        const float* pl; const float* gl; const float* bl; int o, Col;
        if (ch < 128)      { pl = p.part0; gl = p.g0; bl = p.be0; o = ch;       Col = 128; }
        else if (ch < 256) { pl = p.part1; gl = p.g1; bl = p.be1; o = ch - 128; Col = 128; }
        else if (ch < 320) { pl = p.part2; gl = p.g2; bl = p.be2; o = ch - 256; Col = 64;  }
        else               { pl = p.part3; gl = p.g3; bl = p.be3; o = ch - 320; Col = 64;  }
        float s  = pl[o * 2]     + pl[(Col + o) * 2];
        float s2 = pl[o * 2 + 1] + pl[(Col + o) * 2 + 1];
        const float invc = 1.f / 131072.f;
        float mu = s * invc;
        float var = s2 * invc - mu * mu;
        float rs = rsqrtf(var + 1e-5f);
        float sc = gl[o] * rs;
        shsc[ch] = sc;
        shsh[ch] = bl[o] - mu * sc;
    }
    __syncthreads();
    int tn4 = (t & 15) * 4, to4 = (t >> 4) * 4;
    int n0 = blockIdx.x * 64, o0 = blockIdx.y * 64, b = blockIdx.z;
    int cc0 = t >> 6, nn0 = t & 63;
    float4 acc[4];
#pragma unroll
    for (int i = 0; i < 4; ++i) acc[i] = make_float4(0.f,0.f,0.f,0.f);
    for (int c0 = 0; c0 < 384; c0 += 32) {
        float rx[8], rw[8];
#pragma unroll
        for (int k = 0; k < 8; ++k) {
            int cc = cc0 + k * 4;
            rx[k] = xconM[((size_t)b * 384 + c0 + cc) * NPTS + n0 + nn0];
            rw[k] = wlT[(size_t)(c0 + cc) * 384 + o0 + nn0];
        }
#pragma unroll
        for (int k = 0; k < 8; ++k) {
            int cc = cc0 + k * 4;
            float y = fmaf(rx[k], shsc[c0 + cc], shsh[c0 + cc]);
            rx[k] = y >= 0.f ? y : 0.2f * y;
        }
        __syncthreads();
#pragma unroll
        for (int k = 0; k < 8; ++k) {
            int cc = cc0 + k * 4;
            Xs[cc * 64 + nn0] = rx[k];
            Wl[cc * 68 + nn0] = rw[k];
        }
        __syncthreads();
#pragma unroll 4
        for (int cc = 0; cc < 32; ++cc) {
            float4 xv = *(const float4*)&Xs[cc * 64 + tn4];
            float4 wv = *(const float4*)&Wl[cc * 68 + to4];
            float wvv[4] = {wv.x, wv.y, wv.z, wv.w};
#pragma unroll
            for (int i = 0; i < 4; ++i) {
                acc[i].x = fmaf(wvv[i], xv.x, acc[i].x);
                acc[i].y = fmaf(wvv[i], xv.y, acc[i].y);
                acc[i].z = fmaf(wvv[i], xv.z, acc[i].z);
                acc[i].w = fmaf(wvv[i], xv.w, acc[i].w);
            }
        }
    }
#pragma unroll
    for (int i = 0; i < 4; ++i)
        *(float4*)&out[((size_t)b * 384 + o0 + to4 + i) * NPTS + n0 + tn4] = acc[i];
}

extern "C" void kernel_launch(void* const* d_in, const int* in_sizes, int n_in,
                              void* d_out, int out_size, void* d_ws, size_t ws_size,
                              hipStream_t stream) {
    const float* x  = (const float*)d_in[0];
    const float* w[4]  = {(const float*)d_in[1], (const float*)d_in[4], (const float*)d_in[7], (const float*)d_in[10]};
    const float* g[4]  = {(const float*)d_in[2], (const float*)d_in[5], (const float*)d_in[8], (const float*)d_in[11]};
    const float* be[4] = {(const float*)d_in[3], (const float*)d_in[6], (const float*)d_in[9], (const float*)d_in[12]};
    const float* wl = (const float*)d_in[13];

    float* ws    = (float*)d_ws;
    float* xconM = ws;                       // 2*384*1024 = 786432 (pre-BN maxY concat)
    float* A     = xconM + 786432;           // 262144
    float* Bv    = A + 262144;               // 262144
    float* sq    = Bv + 262144;              // 2048
    float* Dp    = sq + 2048;                // 4*2*1024*224 = 1835008
    float* part  = Dp + 1835008;             // 4 layers * 512 = 2048
    float* wt    = part + 2048;              // 270336 (transposed weights)
    int*   idx   = (int*)(wt + 270336);      // 131072 ints

    kprep<<<204, 256, 0, stream>>>(w[0], w[1], w[2], w[3], wl, wt);

    struct LC { const float* xin; int bstride; int Cin; int Co; int nch; int chOut;
                const float* wtA; const float* wtB; };
    LC L[4] = {
        { x,                  256 * 1024, 256, 128, 4, 0,   wt,          wt + 32768  },
        { xconM,              384 * 1024, 128, 128, 2, 128, wt + 65536,  wt + 81920  },
        { xconM + 128 * 1024, 384 * 1024, 128, 64,  2, 256, wt + 98304,  wt + 106496 },
        { xconM + 256 * 1024, 384 * 1024, 64,  64,  1, 320, wt + 114688, wt + 118784 },
    };

    for (int l = 0; l < 4; ++l) {
        GP gp;
        gp.xin = L[l].xin; gp.bstride = L[l].bstride; gp.Cin = L[l].Cin; gp.Co = L[l].Co;
        gp.nch = L[l].nch; gp.applyBN = (l > 0);
        gp.WtA = L[l].wtA; gp.WtB = L[l].wtB;
        gp.partPrev = (l > 0) ? part + (l - 1) * 512 : nullptr;
        gp.gPrev = (l > 0) ? g[l - 1] : nullptr;
        gp.bePrev = (l > 0) ? be[l - 1] : nullptr;
        gp.A = A; gp.Bv = Bv; gp.sq = sq; gp.Dp = Dp;
        int nAB = 16 * (L[l].Co >> 6) * BATCH;
        int nDist = L[l].nch * 32 * BATCH;
        kgemm  <<<nAB + nDist, 256, 0, stream>>>(gp);
        if (L[l].nch == 4)      kselect<4><<<dim3(NPTS / 4, BATCH), 256, 0, stream>>>(Dp, sq, idx);
        else if (L[l].nch == 2) kselect<2><<<dim3(NPTS / 4, BATCH), 256, 0, stream>>>(Dp, sq, idx);
        else                    kselect<1><<<dim3(NPTS / 4, BATCH), 256, 0, stream>>>(Dp, sq, idx);
        kagg   <<<dim3(L[l].Co, BATCH), 256, 0, stream>>>(A, Bv, idx, L[l].Co, xconM, L[l].chOut, part + l * 512);
    }

    FP fp;
    fp.part0 = part; fp.part1 = part + 512; fp.part2 = part + 1024; fp.part3 = part + 1536;
    fp.g0 = g[0]; fp.g1 = g[1]; fp.g2 = g[2]; fp.g3 = g[3];
    fp.be0 = be[0]; fp.be1 = be[1]; fp.be2 = be[2]; fp.be3 = be[3];
    kfinal<<<dim3(16, 6, BATCH), 256, 0, stream>>>(xconM, wt + 122880, fp, (float*)d_out);
}

// Round 7
// 277.142 us; speedup vs baseline: 2.6100x; 1.4184x over previous
//
#include <hip/hip_runtime.h>
#include <math.h>

#define NPTS 1024
#define CAND 224   // 7*32
#define KEFF 64
#define BATCH 2
#define NEGV -1e30f

// ================================================================ weight prep
// Transpose weights to c-major once per call. 32x32 tiles via LDS.
__global__ __launch_bounds__(256) void kprep(const float* __restrict__ w0, const float* __restrict__ w1,
                                             const float* __restrict__ w2, const float* __restrict__ w3,
                                             const float* __restrict__ wl, float* __restrict__ wt) {
    __shared__ float tA[32][33];
    __shared__ float tB[32][33];
    int id = blockIdx.x;
    int t = threadIdx.x;
    int row = t >> 5, col = t & 31;
    const float* W = w0; int Cin = 256, Co = 128; float* WtA = wt; float* WtB = wt + 32768;
    int tc = 0, to = 0; bool isWL = false;
    if (id < 32)      { int r = id;      tc = r >> 2; to = r & 3; }
    else if (id < 48) { W = w1; Cin = 128; Co = 128; WtA = wt + 65536;  WtB = wt + 81920;  int r = id - 32; tc = r >> 2; to = r & 3; }
    else if (id < 56) { W = w2; Cin = 128; Co = 64;  WtA = wt + 98304;  WtB = wt + 106496; int r = id - 48; tc = r >> 1; to = r & 1; }
    else if (id < 60) { W = w3; Cin = 64;  Co = 64;  WtA = wt + 114688; WtB = wt + 118784; int r = id - 56; tc = r >> 1; to = r & 1; }
    else { isWL = true; int r = id - 60; tc = r / 12; to = r % 12; }
    if (!isWL) {
#pragma unroll
        for (int r = 0; r < 4; ++r) {
            int o = to * 32 + row + r * 8;
            int c = tc * 32 + col;
            float va = W[(size_t)o * 2 * Cin + c];
            tA[row + r * 8][col] = va;
            tB[row + r * 8][col] = W[(size_t)o * 2 * Cin + Cin + c] - va;
        }
        __syncthreads();
#pragma unroll
        for (int r = 0; r < 4; ++r) {
            int c = tc * 32 + row + r * 8;
            int o = to * 32 + col;
            WtA[(size_t)c * Co + o] = tA[col][row + r * 8];
            WtB[(size_t)c * Co + o] = tB[col][row + r * 8];
        }
    } else {
        float* wlT = wt + 122880;
#pragma unroll
        for (int r = 0; r < 4; ++r) {
            int o = to * 32 + row + r * 8;
            int c = tc * 32 + col;
            tA[row + r * 8][col] = wl[(size_t)o * 384 + c];
        }
        __syncthreads();
#pragma unroll
        for (int r = 0; r < 4; ++r) {
            int c = tc * 32 + row + r * 8;
            int o = to * 32 + col;
            wlT[(size_t)c * 384 + o] = tA[col][row + r * 8];
        }
    }
}

// ================================================================ fused GEMM (A/Bv/sq) + banded gram
struct GP {
    const float* xin; int bstride; int Cin; int Co; int nch; int applyBN;
    const float* WtA; const float* WtB;
    const float* partPrev; const float* gPrev; const float* bePrev;
    float* A; float* Bv; float* sq; float* Dp;
};

__global__ __launch_bounds__(256) void kgemm(GP p) {
    __shared__ float smem[7168];      // roleA: Xs[0..2047], Wta[2048..4223], Wtb[4224..6399]; roleB: Xc[32][224]
    __shared__ float shsc[128];
    __shared__ float shsh[128];
    int t = threadIdx.x;
    if (p.applyBN && t < p.Cin) {
        const float* pp = p.partPrev;
        float s  = pp[t * 2]     + pp[(p.Cin + t) * 2];
        float s2 = pp[t * 2 + 1] + pp[(p.Cin + t) * 2 + 1];
        const float invc = 1.f / 131072.f;
        float mu = s * invc;
        float var = s2 * invc - mu * mu;
        float rs = rsqrtf(var + 1e-5f);
        float sc = p.gPrev[t] * rs;
        shsc[t] = sc;
        shsh[t] = p.bePrev[t] - mu * sc;
    }
    __syncthreads();
    int nABx = 16 * (p.Co >> 6) * BATCH;
    if ((int)blockIdx.x < nABx) {
        // ---------------- role A: A = WtA^T x, Bv = WtB^T x, sq
        int id = blockIdx.x;
        int nt = id & 15; int rest = id >> 4;
        int nOT = p.Co >> 6;
        int ot = rest % nOT; int b = rest / nOT;
        int tn4 = (t & 15) * 4, to4 = (t >> 4) * 4;
        int n0 = nt * 64, o0 = ot * 64;
        const float* xb = p.xin + (size_t)b * p.bstride + n0;
        float* Xs = smem; float* Wta = smem + 2048; float* Wtb = smem + 4224;
        float4 a[4], bb[4], s4;
#pragma unroll
        for (int i = 0; i < 4; ++i) { a[i] = make_float4(0.f,0.f,0.f,0.f); bb[i] = make_float4(0.f,0.f,0.f,0.f); }
        s4 = make_float4(0.f,0.f,0.f,0.f);
        int cc0 = t >> 6, nn0 = t & 63;   // e = t + k*256 -> cc = cc0 + k*4, nn/oo = nn0
        for (int c0 = 0; c0 < p.Cin; c0 += 32) {
            float rx[8], ra[8], rb[8];
#pragma unroll
            for (int k = 0; k < 8; ++k) {
                int cc = cc0 + k * 4;
                rx[k] = xb[(size_t)(c0 + cc) * NPTS + nn0];
                ra[k] = p.WtA[(size_t)(c0 + cc) * p.Co + o0 + nn0];
                rb[k] = p.WtB[(size_t)(c0 + cc) * p.Co + o0 + nn0];
            }
            if (p.applyBN) {
#pragma unroll
                for (int k = 0; k < 8; ++k) {
                    int cc = cc0 + k * 4;
                    float y = fmaf(rx[k], shsc[c0 + cc], shsh[c0 + cc]);
                    rx[k] = y >= 0.f ? y : 0.2f * y;
                }
            }
            __syncthreads();   // prev-tile compute done before overwrite
#pragma unroll
            for (int k = 0; k < 8; ++k) {
                int cc = cc0 + k * 4;
                Xs[cc * 64 + nn0] = rx[k];
                Wta[cc * 68 + nn0] = ra[k];
                Wtb[cc * 68 + nn0] = rb[k];
            }
            __syncthreads();
#pragma unroll 4
            for (int cc = 0; cc < 32; ++cc) {
                float4 xv = *(const float4*)&Xs[cc * 64 + tn4];
                float4 wa = *(const float4*)&Wta[cc * 68 + to4];
                float4 wb = *(const float4*)&Wtb[cc * 68 + to4];
                s4.x = fmaf(xv.x, xv.x, s4.x);
                s4.y = fmaf(xv.y, xv.y, s4.y);
                s4.z = fmaf(xv.z, xv.z, s4.z);
                s4.w = fmaf(xv.w, xv.w, s4.w);
                float wav[4] = {wa.x, wa.y, wa.z, wa.w};
                float wbv[4] = {wb.x, wb.y, wb.z, wb.w};
#pragma unroll
                for (int i = 0; i < 4; ++i) {
                    a[i].x  = fmaf(wav[i], xv.x, a[i].x);
                    a[i].y  = fmaf(wav[i], xv.y, a[i].y);
                    a[i].z  = fmaf(wav[i], xv.z, a[i].z);
                    a[i].w  = fmaf(wav[i], xv.w, a[i].w);
                    bb[i].x = fmaf(wbv[i], xv.x, bb[i].x);
                    bb[i].y = fmaf(wbv[i], xv.y, bb[i].y);
                    bb[i].z = fmaf(wbv[i], xv.z, bb[i].z);
                    bb[i].w = fmaf(wbv[i], xv.w, bb[i].w);
                }
            }
        }
        int n = n0 + tn4;
        if (ot == 0 && to4 == 0)
            *(float4*)&p.sq[b * NPTS + n] = s4;
#pragma unroll
        for (int i = 0; i < 4; ++i) {
            int o = o0 + to4 + i;
            size_t off = ((size_t)(b * p.Co + o)) * NPTS + n;
            *(float4*)&p.A[off] = a[i];
            *(float4*)&p.Bv[off] = bb[i];
        }
    } else {
        // ---------------- role B: banded gram partials
        int id2 = blockIdx.x - nABx;
        int chunk = id2 % p.nch; int rest = id2 / p.nch;
        int i = rest & 31; int b = rest >> 5;
        const float* xb = p.xin + (size_t)b * p.bstride;
        float* Xc = smem;
        int q = t >> 3;
        int wg = t & 7;
        float acc[28];
#pragma unroll
        for (int j = 0; j < 28; ++j) acc[j] = 0.f;
        for (int sub = 0; sub < 2; ++sub) {
            int c0 = chunk * 64 + sub * 32;
            if (c0 >= p.Cin) break;
            float r[28];
            int rcc[28], rw[28];
#pragma unroll
            for (int k = 0; k < 28; ++k) {
                int e = t + k * 256;
                int cc = e / CAND;
                int w  = e - cc * CAND;
                rcc[k] = cc; rw[k] = w;
                int wb = i - 3 + (w >> 5);
                wb = wb < 0 ? 0 : (wb > 31 ? 31 : wb);
                r[k] = xb[(size_t)(c0 + cc) * NPTS + wb * 32 + (w & 31)];
            }
            if (p.applyBN) {
#pragma unroll
                for (int k = 0; k < 28; ++k) {
                    float y = fmaf(r[k], shsc[c0 + rcc[k]], shsh[c0 + rcc[k]]);
                    r[k] = y >= 0.f ? y : 0.2f * y;
                }
            }
            __syncthreads();
#pragma unroll
            for (int k = 0; k < 28; ++k)
                Xc[rcc[k] * CAND + rw[k]] = r[k];
            __syncthreads();
            for (int cc = 0; cc < 32; ++cc) {
                float qv = Xc[cc * CAND + 96 + q];
                const float4* row = (const float4*)&Xc[cc * CAND + wg * 28];
#pragma unroll
                for (int j4 = 0; j4 < 7; ++j4) {
                    float4 v = row[j4];
                    acc[j4 * 4 + 0] = fmaf(qv, v.x, acc[j4 * 4 + 0]);
                    acc[j4 * 4 + 1] = fmaf(qv, v.y, acc[j4 * 4 + 1]);
                    acc[j4 * 4 + 2] = fmaf(qv, v.z, acc[j4 * 4 + 2]);
                    acc[j4 * 4 + 3] = fmaf(qv, v.w, acc[j4 * 4 + 3]);
                }
            }
        }
        int n = i * 32 + q;
        size_t base = (((size_t)chunk * BATCH + b) * NPTS + n) * CAND + wg * 28;
        float4* outp = (float4*)&p.Dp[base];
#pragma unroll
        for (int j4 = 0; j4 < 7; ++j4)
            outp[j4] = make_float4(acc[j4 * 4], acc[j4 * 4 + 1], acc[j4 * 4 + 2], acc[j4 * 4 + 3]);
    }
}

// ================================================================ top-64 rank selection (64-bit key compares)
// key = (sortable(d) << 8) | (255 - w): key(w') > key(w)  <=>  d' > d, or d'==d and w' < w.
template<int NCH>
__global__ __launch_bounds__(256) void kselect(const float* __restrict__ Dp,
                                               const float* __restrict__ sq,
                                               int* __restrict__ idxo) {
    __shared__ ulonglong2 Dsh2[4][112];   // 7168 B; per-wave row of 224 keys
    unsigned long long* Dsh = (unsigned long long*)Dsh2;
    int t = threadIdx.x;
    int wv = t >> 6, l = t & 63;
    int b = blockIdx.y;
    int n = blockIdx.x * 4 + wv;
    int i = n >> 5;
    float sqn = sq[b * NPTS + n];
    float pr[4][NCH];
    float sqw[4];
    // phase 1a: issue ALL loads (independent) before any combine
#pragma unroll
    for (int j = 0; j < 4; ++j) {
        int w = l + 64 * j;
        if (w < CAND) {
            size_t off = ((size_t)b * NPTS + n) * CAND + w;
#pragma unroll
            for (int ch = 0; ch < NCH; ++ch)
                pr[j][ch] = Dp[off + (size_t)ch * (BATCH * NPTS * CAND)];
            int wb = i - 3 + (w >> 5);
            int wbc = wb < 0 ? 0 : (wb > 31 ? 31 : wb);
            sqw[j] = sq[b * NPTS + wbc * 32 + (w & 31)];
        }
    }
    // phase 1b: combine (ascending ch order preserved -> bit-identical d) + build keys
    unsigned long long kj[4];
#pragma unroll
    for (int j = 0; j < 4; ++j) {
        int w = l + 64 * j;
        if (w < CAND) {
            float s = 0.f;
#pragma unroll
            for (int ch = 0; ch < NCH; ++ch) s += pr[j][ch];
            int wb = i - 3 + (w >> 5);
            bool valid = (wb >= 0) && (wb < 32);
            float d = 2.f * s - sqn - sqw[j];
            d = valid ? d : NEGV;
            unsigned u = __float_as_uint(d);
            u ^= ((unsigned)((int)u >> 31)) | 0x80000000u;   // monotone float->uint
            unsigned long long key = ((unsigned long long)u << 8) | (unsigned long long)(255 - w);
            kj[j] = key;
            Dsh[wv * 224 + w] = key;
        } else {
            kj[j] = 0ull;
        }
    }
    __syncthreads();
    int cnt[4] = {0, 0, 0, 0};
    const ulonglong2* row = Dsh2[wv];
#pragma unroll 2
    for (int w2 = 0; w2 < 112; w2 += 4) {   // 8 keys per iter, 4 b128 loads in flight
        ulonglong2 k0 = row[w2], k1 = row[w2 + 1], k2 = row[w2 + 2], k3 = row[w2 + 3];
#pragma unroll
        for (int j = 0; j < 4; ++j) {
            unsigned long long kk = kj[j];
            cnt[j] += (int)(k0.x > kk) + (int)(k0.y > kk) + (int)(k1.x > kk) + (int)(k1.y > kk)
                    + (int)(k2.x > kk) + (int)(k2.y > kk) + (int)(k3.x > kk) + (int)(k3.y > kk);
        }
    }
#pragma unroll
    for (int j = 0; j < 4; ++j) {
        int w = l + 64 * j;
        if (w < CAND && cnt[j] < KEFF)
            idxo[((size_t)b * NPTS + n) * KEFF + cnt[j]] = (i - 3) * 32 + w;
    }
}

// ================================================================ gather + max/S1/S2; maxY -> xconM (pre-BN)
__global__ __launch_bounds__(256) void kagg(const float* __restrict__ A, const float* __restrict__ Bv,
                                            const int* __restrict__ idx, int Co,
                                            float* __restrict__ xconM, int chOut,
                                            float* __restrict__ part) {
    __shared__ float Ash[NPTS];
    __shared__ float red[256];
    int o = blockIdx.x, b = blockIdx.y, t = threadIdx.x;
    size_t rowoff = ((size_t)(b * Co + o)) * NPTS;
    {
        float rA[4];
#pragma unroll
        for (int r = 0; r < 4; ++r) rA[r] = A[rowoff + r * 256 + t];
#pragma unroll
        for (int r = 0; r < 4; ++r) Ash[r * 256 + t] = rA[r];
    }
    __syncthreads();
    float sum = 0.f, sumsq = 0.f;
    for (int r = 0; r < 4; ++r) {
        int n = r * 256 + t;
        const int4* ip = (const int4*)&idx[((size_t)b * NPTS + n) * KEFF];
        float s1 = 0.f, s2 = 0.f, mx = -3.4e38f;
#pragma unroll
        for (int kk = 0; kk < KEFF / 4; ++kk) {
            int4 v4 = ip[kk];
            float a0 = Ash[v4.x], a1 = Ash[v4.y], a2 = Ash[v4.z], a3 = Ash[v4.w];
            s1 += a0 + a1 + a2 + a3;
            s2 += a0 * a0 + a1 * a1 + a2 * a2 + a3 * a3;
            mx = fmaxf(mx, fmaxf(fmaxf(a0, a1), fmaxf(a2, a3)));
        }
        float bv = Bv[rowoff + n];
        xconM[((size_t)b * 384 + chOut + o) * NPTS + n] = mx + bv;
        sum   += s1 + 64.f * bv;
        sumsq += s2 + 2.f * bv * s1 + 64.f * bv * bv;
    }
    red[t] = sum; __syncthreads();
    for (int s = 128; s > 0; s >>= 1) { if (t < s) red[t] += red[t + s]; __syncthreads(); }
    if (t == 0) part[((size_t)(b * Co + o)) * 2 + 0] = red[0];
    __syncthreads();
    red[t] = sumsq; __syncthreads();
    for (int s = 128; s > 0; s >>= 1) { if (t < s) red[t] += red[t + s]; __syncthreads(); }
    if (t == 0) part[((size_t)(b * Co + o)) * 2 + 1] = red[0];
}

// ================================================================ final GEMM with BN+leaky on load
struct FP {
    const float* part0; const float* part1; const float* part2; const float* part3;
    const float* g0; const float* g1; const float* g2; const float* g3;
    const float* be0; const float* be1; const float* be2; const float* be3;
};

__global__ __launch_bounds__(256) void kfinal(const float* __restrict__ xconM,
                                              const float* __restrict__ wlT, FP p,
                                              float* __restrict__ out) {
    __shared__ float Xs[2048];
    __shared__ float Wl[2176];
    __shared__ float shsc[384];
    __shared__ float shsh[384];
    int t = threadIdx.x;
    for (int ch = t; ch < 384; ch += 256) {
        const float* pl; const float* gl; const float* bl; int o, Col;
        if (ch < 128)      { pl = p.part0; gl = p.g0; bl = p.be0; o = ch;       Col = 128; }
        else if (ch < 256) { pl = p.part1; gl = p.g1; bl = p.be1; o = ch - 128; Col = 128; }
        else if (ch < 320) { pl = p.part2; gl = p.g2; bl = p.be2; o = ch - 256; Col = 64;  }
        else               { pl = p.part3; gl = p.g3; bl = p.be3; o = ch - 320; Col = 64;  }
        float s  = pl[o * 2]     + pl[(Col + o) * 2];
        float s2 = pl[o * 2 + 1] + pl[(Col + o) * 2 + 1];
        const float invc = 1.f / 131072.f;
        float mu = s * invc;
        float var = s2 * invc - mu * mu;
        float rs = rsqrtf(var + 1e-5f);
        float sc = gl[o] * rs;
        shsc[ch] = sc;
        shsh[ch] = bl[o] - mu * sc;
    }
    __syncthreads();
    int tn4 = (t & 15) * 4, to4 = (t >> 4) * 4;
    int n0 = blockIdx.x * 64, o0 = blockIdx.y * 64, b = blockIdx.z;
    int cc0 = t >> 6, nn0 = t & 63;
    float4 acc[4];
#pragma unroll
    for (int i = 0; i < 4; ++i) acc[i] = make_float4(0.f,0.f,0.f,0.f);
    for (int c0 = 0; c0 < 384; c0 += 32) {
        float rx[8], rw[8];
#pragma unroll
        for (int k = 0; k < 8; ++k) {
            int cc = cc0 + k * 4;
            rx[k] = xconM[((size_t)b * 384 + c0 + cc) * NPTS + n0 + nn0];
            rw[k] = wlT[(size_t)(c0 + cc) * 384 + o0 + nn0];
        }
#pragma unroll
        for (int k = 0; k < 8; ++k) {
            int cc = cc0 + k * 4;
            float y = fmaf(rx[k], shsc[c0 + cc], shsh[c0 + cc]);
            rx[k] = y >= 0.f ? y : 0.2f * y;
        }
        __syncthreads();
#pragma unroll
        for (int k = 0; k < 8; ++k) {
            int cc = cc0 + k * 4;
            Xs[cc * 64 + nn0] = rx[k];
            Wl[cc * 68 + nn0] = rw[k];
        }
        __syncthreads();
#pragma unroll 4
        for (int cc = 0; cc < 32; ++cc) {
            float4 xv = *(const float4*)&Xs[cc * 64 + tn4];
            float4 wv = *(const float4*)&Wl[cc * 68 + to4];
            float wvv[4] = {wv.x, wv.y, wv.z, wv.w};
#pragma unroll
            for (int i = 0; i < 4; ++i) {
                acc[i].x = fmaf(wvv[i], xv.x, acc[i].x);
                acc[i].y = fmaf(wvv[i], xv.y, acc[i].y);
                acc[i].z = fmaf(wvv[i], xv.z, acc[i].z);
                acc[i].w = fmaf(wvv[i], xv.w, acc[i].w);
            }
        }
    }
#pragma unroll
    for (int i = 0; i < 4; ++i)
        *(float4*)&out[((size_t)b * 384 + o0 + to4 + i) * NPTS + n0 + tn4] = acc[i];
}

extern "C" void kernel_launch(void* const* d_in, const int* in_sizes, int n_in,
                              void* d_out, int out_size, void* d_ws, size_t ws_size,
                              hipStream_t stream) {
    const float* x  = (const float*)d_in[0];
    const float* w[4]  = {(const float*)d_in[1], (const float*)d_in[4], (const float*)d_in[7], (const float*)d_in[10]};
    const float* g[4]  = {(const float*)d_in[2], (const float*)d_in[5], (const float*)d_in[8], (const float*)d_in[11]};
    const float* be[4] = {(const float*)d_in[3], (const float*)d_in[6], (const float*)d_in[9], (const float*)d_in[12]};
    const float* wl = (const float*)d_in[13];

    float* ws    = (float*)d_ws;
    float* xconM = ws;                       // 2*384*1024 = 786432 (pre-BN maxY concat)
    float* A     = xconM + 786432;           // 262144
    float* Bv    = A + 262144;               // 262144
    float* sq    = Bv + 262144;              // 2048
    float* Dp    = sq + 2048;                // 4*2*1024*224 = 1835008
    float* part  = Dp + 1835008;             // 4 layers * 512 = 2048
    float* wt    = part + 2048;              // 270336 (transposed weights)
    int*   idx   = (int*)(wt + 270336);      // 131072 ints

    kprep<<<204, 256, 0, stream>>>(w[0], w[1], w[2], w[3], wl, wt);

    struct LC { const float* xin; int bstride; int Cin; int Co; int nch; int chOut;
                const float* wtA; const float* wtB; };
    LC L[4] = {
        { x,                  256 * 1024, 256, 128, 4, 0,   wt,          wt + 32768  },
        { xconM,              384 * 1024, 128, 128, 2, 128, wt + 65536,  wt + 81920  },
        { xconM + 128 * 1024, 384 * 1024, 128, 64,  2, 256, wt + 98304,  wt + 106496 },
        { xconM + 256 * 1024, 384 * 1024, 64,  64,  1, 320, wt + 114688, wt + 118784 },
    };

    for (int l = 0; l < 4; ++l) {
        GP gp;
        gp.xin = L[l].xin; gp.bstride = L[l].bstride; gp.Cin = L[l].Cin; gp.Co = L[l].Co;
        gp.nch = L[l].nch; gp.applyBN = (l > 0);
        gp.WtA = L[l].wtA; gp.WtB = L[l].wtB;
        gp.partPrev = (l > 0) ? part + (l - 1) * 512 : nullptr;
        gp.gPrev = (l > 0) ? g[l - 1] : nullptr;
        gp.bePrev = (l > 0) ? be[l - 1] : nullptr;
        gp.A = A; gp.Bv = Bv; gp.sq = sq; gp.Dp = Dp;
        int nAB = 16 * (L[l].Co >> 6) * BATCH;
        int nDist = L[l].nch * 32 * BATCH;
        kgemm  <<<nAB + nDist, 256, 0, stream>>>(gp);
        if (L[l].nch == 4)      kselect<4><<<dim3(NPTS / 4, BATCH), 256, 0, stream>>>(Dp, sq, idx);
        else if (L[l].nch == 2) kselect<2><<<dim3(NPTS / 4, BATCH), 256, 0, stream>>>(Dp, sq, idx);
        else                    kselect<1><<<dim3(NPTS / 4, BATCH), 256, 0, stream>>>(Dp, sq, idx);
        kagg   <<<dim3(L[l].Co, BATCH), 256, 0, stream>>>(A, Bv, idx, L[l].Co, xconM, L[l].chOut, part + l * 512);
    }

    FP fp;
    fp.part0 = part; fp.part1 = part + 512; fp.part2 = part + 1024; fp.part3 = part + 1536;
    fp.g0 = g[0]; fp.g1 = g[1]; fp.g2 = g[2]; fp.g3 = g[3];
    fp.be0 = be[0]; fp.be1 = be[1]; fp.be2 = be[2]; fp.be3 = be[3];
    kfinal<<<dim3(16, 6, BATCH), 256, 0, stream>>>(xconM, wt + 122880, fp, (float*)d_out);
}